// Round 17
// baseline (576.869 us; speedup 1.0000x reference)
//
#include <hip/hip_runtime.h>
#include <hip/hip_bf16.h>

#define B_ 2
#define N_ 4096
#define NY 4095          // pooled tree rows per batch
#define TOT 8191

typedef __attribute__((ext_vector_type(8))) short bf16x8;
typedef __attribute__((ext_vector_type(4))) short s16x4;
typedef __attribute__((ext_vector_type(4))) float f32x4;

__device__ inline float b2f(short s) {
  unsigned u = ((unsigned)(unsigned short)s) << 16;
  float f; __builtin_memcpy(&f, &u, 4); return f;
}
__device__ inline short f2bf(float f) {
  unsigned u; __builtin_memcpy(&u, &f, 4);
  return (short)((u + 0x7fffu + ((u >> 16) & 1u)) >> 16);
}
__device__ inline float dot8(bf16x8 a, bf16x8 b) {
  float s = 0.f;
#pragma unroll
  for (int j = 0; j < 8; ++j) s += b2f(a[j]) * b2f(b[j]);
  return s;
}
__device__ inline void gl_lds16(const short* g, short* l) {
  __builtin_amdgcn_global_load_lds(
      (const __attribute__((address_space(1))) void*)g,
      (__attribute__((address_space(3))) void*)l, 16, 0, 0);
}

// ---------------- merged conversions ----------------

struct CvtArgs {
  const float* x;
  const float* w[8];
  const float* woy;
  const float* wkx;
  const float* wvx;
  const float* boy;
  short* xbf;
  short* wts;
  short* woyT;
  float* cbias;
};

__global__ __launch_bounds__(256) void cvt_all(CvtArgs a) {
  __shared__ float tile[64][65];
  int bid = blockIdx.x;
  int tid = threadIdx.x;
  if (bid < 8192) {
    long t = (((long)bid << 8) + tid) << 2;
    float4 v = *(const float4*)(a.x + t);
    s16x4 o; o.x = f2bf(v.x); o.y = f2bf(v.y); o.z = f2bf(v.z); o.w = f2bf(v.w);
    *(s16x4*)(a.xbf + t) = o;
  } else if (bid < 16384) {
    long t = (((long)(bid - 8192) << 8) + tid) << 2;
    int which = (int)(t >> 20);
    const float* sp = a.w[which] + (t & 1048575);
    float4 v = *(const float4*)sp;
    s16x4 o; o.x = f2bf(v.x); o.y = f2bf(v.y); o.z = f2bf(v.z); o.w = f2bf(v.w);
    *(s16x4*)(a.wts + t) = o;
  } else if (bid < 16640) {
    int tb = bid - 16384;
    int tr = (tb >> 4) << 6, tc = (tb & 15) << 6;
    int lc = tid & 63, lr4 = tid >> 6;
    for (int r = lr4; r < 64; r += 4)
      tile[r][lc] = a.woy[(long)(tr + r) * 1024 + tc + lc];
    __syncthreads();
    for (int r = lr4; r < 64; r += 4)
      a.woyT[(long)(tc + r) * 1024 + tr + lc] = f2bf(tile[lc][r]);
  } else {
    int f = ((bid - 16640) << 2) + (tid >> 6);
    int lane = tid & 63;
    const float* row = (f < 1024) ? (a.wkx + (long)f * 1024)
                                  : (a.wvx + (long)(f - 1024) * 1024);
    const float* rp = row + lane * 16;
    const float* bp = a.boy + lane * 16;
    float s = 0.f;
#pragma unroll
    for (int q = 0; q < 4; ++q) {
      float4 wv = *(const float4*)(rp + q * 4);
      float4 bv = *(const float4*)(bp + q * 4);
      s += wv.x * bv.x + wv.y * bv.y + wv.z * bv.z + wv.w * bv.w;
    }
#pragma unroll
    for (int sh = 32; sh >= 1; sh >>= 1) s += __shfl_xor(s, sh);
    if (lane == 0) a.cbias[f] = s;
  }
}

// ---------------- cascade pooling of projected tree (levels 0..3) --------

__global__ __launch_bounds__(256) void pool_cascade(const short* __restrict__ XQ,
                                                    short* __restrict__ QKVp) {
  int bid = blockIdx.x;
  int b = bid / 768;
  int r = bid - b * 768;
  int j16 = r / 3;
  int cb = r - j16 * 3;
  int c = cb * 1024 + threadIdx.x * 4;
  const short* src = XQ + ((long)(b * N_ + j16 * 16)) * 3072 + c;
  short* dstb = QKVp + (long)b * NY * 3072 + c;

  float l1h[4], l2h[4], l3h[4];
#pragma unroll
  for (int p = 0; p < 8; ++p) {
    s16x4 ra = *(const s16x4*)(src + (long)(2 * p) * 3072);
    s16x4 rb = *(const s16x4*)(src + (long)(2 * p + 1) * 3072);
    float l0[4];
    s16x4 o;
#pragma unroll
    for (int j = 0; j < 4; ++j) {
      l0[j] = 0.5f * (b2f(ra[j]) + b2f(rb[j]));
      o[j] = f2bf(l0[j]);
    }
    *(s16x4*)(dstb + (long)(j16 * 8 + p) * 3072) = o;
    if ((p & 1) == 0) {
#pragma unroll
      for (int j = 0; j < 4; ++j) l1h[j] = l0[j];
    } else {
      float l1[4];
      s16x4 o1;
#pragma unroll
      for (int j = 0; j < 4; ++j) {
        l1[j] = 0.5f * (l1h[j] + l0[j]);
        o1[j] = f2bf(l1[j]);
      }
      *(s16x4*)(dstb + (long)(2048 + j16 * 4 + (p >> 1)) * 3072) = o1;
      if (((p >> 1) & 1) == 0) {
#pragma unroll
        for (int j = 0; j < 4; ++j) l2h[j] = l1[j];
      } else {
        float l2[4];
        s16x4 o2;
#pragma unroll
        for (int j = 0; j < 4; ++j) {
          l2[j] = 0.5f * (l2h[j] + l1[j]);
          o2[j] = f2bf(l2[j]);
        }
        *(s16x4*)(dstb + (long)(3072 + j16 * 2 + (p >> 2)) * 3072) = o2;
        if (((p >> 2) & 1) == 0) {
#pragma unroll
          for (int j = 0; j < 4; ++j) l3h[j] = l2[j];
        } else {
          s16x4 o3;
#pragma unroll
          for (int j = 0; j < 4; ++j) o3[j] = f2bf(0.5f * (l3h[j] + l2[j]));
          *(s16x4*)(dstb + (long)(3584 + j16) * 3072) = o3;
        }
      }
    }
  }
}

// pool_qkv_b: levels 4..11 from QKVp level-3 rows (256 rows/b at off 3584)
__global__ __launch_bounds__(256) void pool_qkv_b(short* __restrict__ QKVp) {
  int wid = (blockIdx.x << 2) + (threadIdx.x >> 6);
  if (wid >= B_ * 255) return;
  int lane = threadIdx.x & 63;
  int cb = blockIdx.y << 10;
  int b = wid / 255;
  int r = wid - b * 255;
  int base = 0, size = 128, W = 2;
  while (r >= base + size) { base += size; size >>= 1; W <<= 1; }
  int j = r - base;
  const short* src = QKVp + (long)(b * NY + 3584 + j * W) * 3072 + cb + lane * 16;
  float acc[16];
#pragma unroll
  for (int c = 0; c < 16; ++c) acc[c] = 0.f;
  for (int w = 0; w < W; ++w) {
    const short* rp = src + (long)w * 3072;
    bf16x8 v0 = *(const bf16x8*)rp;
    bf16x8 v1 = *(const bf16x8*)(rp + 8);
#pragma unroll
    for (int jx = 0; jx < 8; ++jx) {
      acc[jx] += b2f(v0[jx]);
      acc[8 + jx] += b2f(v1[jx]);
    }
  }
  float sc = 1.0f / (float)W;
  bf16x8 o0, o1;
#pragma unroll
  for (int jx = 0; jx < 8; ++jx) {
    o0[jx] = f2bf(acc[jx] * sc);
    o1[jx] = f2bf(acc[8 + jx] * sc);
  }
  short* dst = QKVp + (long)(b * NY + 3840 + base + j) * 3072 + cb + lane * 16;
  *(bf16x8*)dst = o0;
  *(bf16x8*)(dst + 8) = o1;
}

// ---------------- GEMM 128x128, BK=64, XOR-swizzle, double-buffered ------

template <int STORE_F32, int HAS_BIAS>
__global__ __launch_bounds__(256) void gemm_bt(const short* __restrict__ A,
                                               const short* __restrict__ W,
                                               void* __restrict__ Cv,
                                               const float* __restrict__ bias,
                                               int Mb, int Ncols, long sA,
                                               long sC) {
  __shared__ __align__(16) short lds[32768];  // 2 bufs x (A 8K + B 8K shorts)
  const int tid = threadIdx.x;
  const int wave = tid >> 6, lane = tid & 63;
  const int row0 = blockIdx.x * 128, col0 = blockIdx.y * 128;
  const short* Ab = A + (long)blockIdx.z * sA;

  f32x4 acc[4][4];
#pragma unroll
  for (int m = 0; m < 4; ++m)
#pragma unroll
    for (int n = 0; n < 4; ++n) acc[m][n] = (f32x4){0.f, 0.f, 0.f, 0.f};

  const short* aS[4];
  const short* wS[4];
  int dBase[4];
#pragma unroll
  for (int r = 0; r < 4; ++r) {
    int P = r * 4096 + wave * 1024 + lane * 16;
    int rw = P >> 7;
    int L = P ^ ((rw & 7) << 4);
    int ks = (L & 127) >> 1;
    int ga = row0 + rw; if (ga > Mb - 1) ga = Mb - 1;
    aS[r] = Ab + ((long)ga << 10) + ks;
    wS[r] = W + ((long)(col0 + rw) << 10) + ks;
    dBase[r] = r * 2048 + wave * 512;  // shorts, wave-uniform
  }

  const int fr = lane & 15, fq = lane >> 4;
  const int wr = (wave >> 1) * 64, wc = (wave & 1) * 64;

  int offA[4][2], offB[4][2];
#pragma unroll
  for (int m = 0; m < 4; ++m)
#pragma unroll
    for (int kh = 0; kh < 2; ++kh) {
      int rwA = wr + m * 16 + fr;
      int LA = rwA * 128 + kh * 64 + fq * 16;
      offA[m][kh] = LA ^ ((rwA & 7) << 4);
      int rwB = wc + m * 16 + fr;
      int LB = rwB * 128 + kh * 64 + fq * 16;
      offB[m][kh] = LB ^ ((rwB & 7) << 4);
    }

  auto stage = [&](int kk, int buf) {
    short* lA = lds + buf * 16384;
    short* lB = lA + 8192;
#pragma unroll
    for (int r = 0; r < 4; ++r) gl_lds16(aS[r] + kk, lA + dBase[r]);
#pragma unroll
    for (int r = 0; r < 4; ++r) gl_lds16(wS[r] + kk, lB + dBase[r]);
  };
  auto compute = [&](int buf) {
    const char* bA = (const char*)(lds + buf * 16384);
    const char* bB = bA + 16384;
#pragma unroll
    for (int kh = 0; kh < 2; ++kh) {
      bf16x8 af[4], bw[4];
#pragma unroll
      for (int m = 0; m < 4; ++m)
        af[m] = *(const bf16x8*)(bA + offA[m][kh]);
#pragma unroll
      for (int n = 0; n < 4; ++n)
        bw[n] = *(const bf16x8*)(bB + offB[n][kh]);
#pragma unroll
      for (int m = 0; m < 4; ++m)
#pragma unroll
        for (int n = 0; n < 4; ++n)
          acc[m][n] = __builtin_amdgcn_mfma_f32_16x16x32_bf16(af[m], bw[n],
                                                              acc[m][n], 0, 0,
                                                              0);
    }
  };

  stage(0, 0);
  asm volatile("s_waitcnt vmcnt(0)" ::: "memory");
  __builtin_amdgcn_s_barrier();
  int cur = 0;
#pragma unroll 1
  for (int t = 0; t < 15; ++t) {
    stage((t + 1) * 64, cur ^ 1);
    compute(cur);
    asm volatile("s_waitcnt vmcnt(0)" ::: "memory");
    __builtin_amdgcn_s_barrier();
    cur ^= 1;
  }
  compute(cur);

#pragma unroll
  for (int n = 0; n < 4; ++n) {
    int col = col0 + wc + n * 16 + fr;
    float bv = HAS_BIAS ? bias[col] : 0.f;
#pragma unroll
    for (int m = 0; m < 4; ++m) {
#pragma unroll
      for (int q = 0; q < 4; ++q) {
        int row = row0 + wr + m * 16 + fq * 4 + q;
        if (row < Mb) {
          long off = (long)blockIdx.z * sC + (long)row * Ncols + col;
          float v = acc[m][n][q] + bv;
          if (STORE_F32) ((float*)Cv)[off] = v;
          else ((short*)Cv)[off] = f2bf(v);
        }
      }
    }
  }
}

// ---------------- split-K chain GEMM (latency-optimized) ----------------
// KSTEPS=16 -> KS=2 ; KSTEPS=8 -> KS=4 ; KSTEPS=4 -> KS=8 (deep levels:
// halves the per-block pipeline depth; schedule verified valid at KSTEPS=4).

template <int KSTEPS>
__global__ __launch_bounds__(256) void gemm_sk(const short* __restrict__ A,
                                               const short* __restrict__ W,
                                               float* __restrict__ part,
                                               int Mrows, long sA) {
  __shared__ __align__(16) short lds[32768];
  const int tid = threadIdx.x;
  const int wave = tid >> 6, lane = tid & 63;
  const int mt = blockIdx.x >> 4, nt = blockIdx.x & 15;
  const int ks = blockIdx.y;
  const int KSPLIT = 32 / KSTEPS;
  const int row0 = mt * 128, col0 = nt * 128;
  const short* Ab = A + (long)blockIdx.z * sA;

  f32x4 acc[4][4];
#pragma unroll
  for (int m = 0; m < 4; ++m)
#pragma unroll
    for (int n = 0; n < 4; ++n) acc[m][n] = (f32x4){0.f, 0.f, 0.f, 0.f};

  const int sr = lane >> 2;
  const int sk = (lane & 3) * 8;
  const int ra0 = wave * 32 + sr;
  const int ra1 = ra0 + 16;
  const int ga0 = (row0 + ra0 < Mrows) ? (row0 + ra0) : (Mrows - 1);
  const int ga1 = (row0 + ra1 < Mrows) ? (row0 + ra1) : (Mrows - 1);
  const long kbase = (long)ks * KSTEPS * 32;
  const short* aP0 = Ab + ((long)ga0 << 10) + kbase + sk;
  const short* aP1 = Ab + ((long)ga1 << 10) + kbase + sk;
  const short* wP0 = W + ((long)(col0 + ra0) << 10) + kbase + sk;
  const short* wP1 = W + ((long)(col0 + ra1) << 10) + kbase + sk;
  const int dA0 = (wave * 2 + 0) * 512, dA1 = (wave * 2 + 1) * 512;
  const int dB0 = 4096 + dA0, dB1 = 4096 + dA1;

  const int fr = lane & 15, fq = lane >> 4;
  const int wr = (wave >> 1) * 64, wc = (wave & 1) * 64;

  auto stage = [&](int kt) {
    short* sb = lds + (kt & 3) * 8192;
    const long ko = (long)kt * 32;
    gl_lds16(aP0 + ko, sb + dA0);
    gl_lds16(aP1 + ko, sb + dA1);
    gl_lds16(wP0 + ko, sb + dB0);
    gl_lds16(wP1 + ko, sb + dB1);
  };
  auto compute = [&](int s) {
    const short* bA = lds + s * 8192;
    const short* bB = bA + 4096;
    bf16x8 af[4], bw[4];
#pragma unroll
    for (int m = 0; m < 4; ++m)
      af[m] = *(const bf16x8*)&bA[(wr + m * 16 + fr) * 32 + fq * 8];
#pragma unroll
    for (int n = 0; n < 4; ++n)
      bw[n] = *(const bf16x8*)&bB[(wc + n * 16 + fr) * 32 + fq * 8];
#pragma unroll
    for (int m = 0; m < 4; ++m)
#pragma unroll
      for (int n = 0; n < 4; ++n)
        acc[m][n] = __builtin_amdgcn_mfma_f32_16x16x32_bf16(af[m], bw[n],
                                                            acc[m][n], 0, 0, 0);
  };

  stage(0); stage(1); stage(2);
#pragma unroll 1
  for (int j = 0; j + 4 <= KSTEPS; ++j) {
    asm volatile("s_waitcnt vmcnt(8)" ::: "memory");
    __builtin_amdgcn_s_barrier();
    compute(j & 3);
    stage(j + 3);
  }
  asm volatile("s_waitcnt vmcnt(8)" ::: "memory");
  __builtin_amdgcn_s_barrier();
  compute((KSTEPS - 3) & 3);
  asm volatile("s_waitcnt vmcnt(4)" ::: "memory");
  __builtin_amdgcn_s_barrier();
  compute((KSTEPS - 2) & 3);
  asm volatile("s_waitcnt vmcnt(0)" ::: "memory");
  __builtin_amdgcn_s_barrier();
  compute((KSTEPS - 1) & 3);

  float* pb = part + ((long)(blockIdx.z * KSPLIT + ks) * Mrows) * 2048;
#pragma unroll
  for (int n = 0; n < 4; ++n) {
    int col = col0 + wc + n * 16 + fr;
#pragma unroll
    for (int m = 0; m < 4; ++m) {
#pragma unroll
      for (int q = 0; q < 4; ++q) {
        int row = row0 + wr + m * 16 + fq * 4 + q;
        if (row < Mrows) pb[(long)row * 2048 + col] = acc[m][n][q];
      }
    }
  }
}

// ---------------- per-level 3-key attention (bf16 children) -------------

__global__ __launch_bounds__(256) void attn_level(
    const short* __restrict__ QKVp, const short* __restrict__ childK, int cs,
    short* __restrict__ ao, int pc, int off, int lgpc) {
  int wid = (blockIdx.x << 2) + (threadIdx.x >> 6);
  if (wid >= B_ * pc) return;
  int lane = threadIdx.x & 63;
  int b = wid >> lgpc;
  int p = wid & (pc - 1);
  int c = lane * 8;
  const short* prow = QKVp + (long)(b * NY + off + p) * 3072 + c;
  const short* c0r = childK + (long)((b * pc + p) * 2) * cs + c;
  const short* c1r = c0r + cs;
  bf16x8 q0 = *(const bf16x8*)(prow);
  bf16x8 q1 = *(const bf16x8*)(prow + 512);
  bf16x8 kp0 = *(const bf16x8*)(prow + 1024);
  bf16x8 kp1 = *(const bf16x8*)(prow + 1536);
  bf16x8 ka0 = *(const bf16x8*)(c0r);
  bf16x8 ka1 = *(const bf16x8*)(c0r + 512);
  bf16x8 kb0 = *(const bf16x8*)(c1r);
  bf16x8 kb1 = *(const bf16x8*)(c1r + 512);
  float d0 = dot8(q0, kp0), d1 = dot8(q1, kp1);
  float d2 = dot8(q0, ka0), d3 = dot8(q1, ka1);
  float d4 = dot8(q0, kb0), d5 = dot8(q1, kb1);
#pragma unroll
  for (int s = 1; s <= 4; s <<= 1) {
    d0 += __shfl_xor(d0, s); d1 += __shfl_xor(d1, s);
    d2 += __shfl_xor(d2, s); d3 += __shfl_xor(d3, s);
    d4 += __shfl_xor(d4, s); d5 += __shfl_xor(d5, s);
  }
  d0 *= 0.125f; d1 *= 0.125f; d2 *= 0.125f;
  d3 *= 0.125f; d4 *= 0.125f; d5 *= 0.125f;
  float mA = fmaxf(d0, fmaxf(d2, d4));
  float e0 = __expf(d0 - mA), e2 = __expf(d2 - mA), e4 = __expf(d4 - mA);
  float iA = 1.f / (e0 + e2 + e4);
  e0 *= iA; e2 *= iA; e4 *= iA;
  float mB = fmaxf(d1, fmaxf(d3, d5));
  float e1 = __expf(d1 - mB), e3 = __expf(d3 - mB), e5 = __expf(d5 - mB);
  float iB = 1.f / (e1 + e3 + e5);
  e1 *= iB; e3 *= iB; e5 *= iB;
  bf16x8 vp0 = *(const bf16x8*)(prow + 2048);
  bf16x8 vp1 = *(const bf16x8*)(prow + 2560);
  bf16x8 va0 = *(const bf16x8*)(c0r + 1024);
  bf16x8 va1 = *(const bf16x8*)(c0r + 1536);
  bf16x8 vb0 = *(const bf16x8*)(c1r + 1024);
  bf16x8 vb1 = *(const bf16x8*)(c1r + 1536);
  bf16x8 s0, s1;
#pragma unroll
  for (int j = 0; j < 8; ++j) {
    s0[j] = f2bf(e0 * b2f(vp0[j]) + e2 * b2f(va0[j]) + e4 * b2f(vb0[j]));
    s1[j] = f2bf(e1 * b2f(vp1[j]) + e3 * b2f(va1[j]) + e5 * b2f(vb1[j]));
  }
  short* orow = ao + (long)(b * NY + off + p) * 1024 + c;
  *(bf16x8*)orow = s0;
  *(bf16x8*)(orow + 512) = s1;
}

// ---------------- per-level 3-key attention (f32 split-K partials) -------

template <int KS>
__device__ __forceinline__ void load8sum(const float* p, long kstride,
                                         float* o) {
  float4 a = *(const float4*)p, b = *(const float4*)(p + 4);
  o[0] = a.x; o[1] = a.y; o[2] = a.z; o[3] = a.w;
  o[4] = b.x; o[5] = b.y; o[6] = b.z; o[7] = b.w;
#pragma unroll
  for (int ks = 1; ks < KS; ++ks) {
    const float* q = p + ks * kstride;
    float4 c = *(const float4*)q, d = *(const float4*)(q + 4);
    o[0] += c.x; o[1] += c.y; o[2] += c.z; o[3] += c.w;
    o[4] += d.x; o[5] += d.y; o[6] += d.z; o[7] += d.w;
  }
}
__device__ __forceinline__ float dot8f(bf16x8 a, const float* b) {
  float s = 0.f;
#pragma unroll
  for (int j = 0; j < 8; ++j) s += b2f(a[j]) * b[j];
  return s;
}

template <int KS>
__global__ __launch_bounds__(256) void attn_level_sk(
    const short* __restrict__ QKVp, const float* __restrict__ part,
    short* __restrict__ ao, int pc, int off, int lgpc) {
  int wid = (blockIdx.x << 2) + (threadIdx.x >> 6);
  if (wid >= B_ * pc) return;
  int lane = threadIdx.x & 63;
  int b = wid >> lgpc;
  int p = wid & (pc - 1);
  int c = lane * 8;
  const int cc = pc * 2;
  const long kstride = (long)cc * 2048;
  const short* prow = QKVp + (long)(b * NY + off + p) * 3072 + c;
  const float* c0r = part + (long)(b * KS) * kstride + (long)(p * 2) * 2048 + c;
  const float* c1r = c0r + 2048;
  bf16x8 q0 = *(const bf16x8*)(prow);
  bf16x8 q1 = *(const bf16x8*)(prow + 512);
  bf16x8 kp0 = *(const bf16x8*)(prow + 1024);
  bf16x8 kp1 = *(const bf16x8*)(prow + 1536);
  float ka0[8], ka1[8], kb0[8], kb1[8];
  load8sum<KS>(c0r, kstride, ka0);
  load8sum<KS>(c0r + 512, kstride, ka1);
  load8sum<KS>(c1r, kstride, kb0);
  load8sum<KS>(c1r + 512, kstride, kb1);
  float d0 = dot8(q0, kp0), d1 = dot8(q1, kp1);
  float d2 = dot8f(q0, ka0), d3 = dot8f(q1, ka1);
  float d4 = dot8f(q0, kb0), d5 = dot8f(q1, kb1);
#pragma unroll
  for (int s = 1; s <= 4; s <<= 1) {
    d0 += __shfl_xor(d0, s); d1 += __shfl_xor(d1, s);
    d2 += __shfl_xor(d2, s); d3 += __shfl_xor(d3, s);
    d4 += __shfl_xor(d4, s); d5 += __shfl_xor(d5, s);
  }
  d0 *= 0.125f; d1 *= 0.125f; d2 *= 0.125f;
  d3 *= 0.125f; d4 *= 0.125f; d5 *= 0.125f;
  float mA = fmaxf(d0, fmaxf(d2, d4));
  float e0 = __expf(d0 - mA), e2 = __expf(d2 - mA), e4 = __expf(d4 - mA);
  float iA = 1.f / (e0 + e2 + e4);
  e0 *= iA; e2 *= iA; e4 *= iA;
  float mB = fmaxf(d1, fmaxf(d3, d5));
  float e1 = __expf(d1 - mB), e3 = __expf(d3 - mB), e5 = __expf(d5 - mB);
  float iB = 1.f / (e1 + e3 + e5);
  e1 *= iB; e3 *= iB; e5 *= iB;
  bf16x8 vp0 = *(const bf16x8*)(prow + 2048);
  bf16x8 vp1 = *(const bf16x8*)(prow + 2560);
  float va0[8], va1[8], vb0[8], vb1[8];
  load8sum<KS>(c0r + 1024, kstride, va0);
  load8sum<KS>(c0r + 1536, kstride, va1);
  load8sum<KS>(c1r + 1024, kstride, vb0);
  load8sum<KS>(c1r + 1536, kstride, vb1);
  bf16x8 s0, s1;
#pragma unroll
  for (int j = 0; j < 8; ++j) {
    s0[j] = f2bf(e0 * b2f(vp0[j]) + e2 * va0[j] + e4 * vb0[j]);
    s1[j] = f2bf(e1 * b2f(vp1[j]) + e3 * va1[j] + e5 * vb1[j]);
  }
  short* orow = ao + (long)(b * NY + off + p) * 1024 + c;
  *(bf16x8*)orow = s0;
  *(bf16x8*)(orow + 512) = s1;
}

// ---------------- final 13-key sparse attention ----------------

__global__ __launch_bounds__(256) void attn_final(const short* __restrict__ QKVx,
                                                  short* __restrict__ out) {
  const long XLEN = (long)B_ * N_ * 3072;
  int wid = (blockIdx.x << 2) + (threadIdx.x >> 6);
  int lane = threadIdx.x & 63;
  int b = wid >> 12;
  int i = wid & (N_ - 1);
  int c = lane * 8;
  const short* qrow = QKVx + (long)(b * N_ + i) * 3072;
  bf16x8 q0 = *(const bf16x8*)(qrow + c);
  bf16x8 q1 = *(const bf16x8*)(qrow + 512 + c);

  long offs[13];
  unsigned mbits = 0;
  offs[0] = (long)(b * N_ + i) * 3072 + 1024;
  int ncur = i;
#pragma unroll
  for (int lvl = 0; lvl < 12; ++lvl) {
    int pair, nx;
    if (lvl == 0) { pair = ncur; nx = ncur ^ 1; }
    else { pair = (ncur >> 1) + N_; nx = pair ^ 1; }
    bool valid = nx <= 2 * N_ - 3;
    int r = valid ? nx : (2 * N_ - 2);
    if (valid && pair < nx) mbits |= 1u << (lvl + 1);
    offs[lvl + 1] = (r < N_) ? ((long)(b * N_ + r) * 3072 + 1024)
                             : (XLEN + (long)(b * NY + (r - N_)) * 2048);
    ncur = nx;
  }
  float dA[13], dB[13];
#pragma unroll
  for (int k = 0; k < 13; ++k) {
    const short* kb = QKVx + offs[k];
    dA[k] = dot8(q0, *(const bf16x8*)(kb + c));
    dB[k] = dot8(q1, *(const bf16x8*)(kb + 512 + c));
  }
#pragma unroll
  for (int s = 1; s <= 4; s <<= 1) {
#pragma unroll
    for (int k = 0; k < 13; ++k) {
      dA[k] += __shfl_xor(dA[k], s);
      dB[k] += __shfl_xor(dB[k], s);
    }
  }
  float mA = -1e30f, mB = -1e30f;
#pragma unroll
  for (int k = 0; k < 13; ++k) {
    bool msk = (mbits >> k) & 1;
    dA[k] = msk ? -1e30f : dA[k] * 0.125f;
    dB[k] = msk ? -1e30f : dB[k] * 0.125f;
    mA = fmaxf(mA, dA[k]);
    mB = fmaxf(mB, dB[k]);
  }
  float sA = 0.f, sB = 0.f;
#pragma unroll
  for (int k = 0; k < 13; ++k) {
    dA[k] = __expf(dA[k] - mA); sA += dA[k];
    dB[k] = __expf(dB[k] - mB); sB += dB[k];
  }
  float iA = 1.f / sA, iB = 1.f / sB;
  float o0[8] = {0, 0, 0, 0, 0, 0, 0, 0};
  float o1[8] = {0, 0, 0, 0, 0, 0, 0, 0};
#pragma unroll
  for (int k = 0; k < 13; ++k) {
    const short* vb = QKVx + offs[k] + 1024;
    bf16x8 v0 = *(const bf16x8*)(vb + c);
    bf16x8 v1 = *(const bf16x8*)(vb + 512 + c);
    float wA = dA[k] * iA, wB = dB[k] * iB;
#pragma unroll
    for (int j = 0; j < 8; ++j) {
      o0[j] += wA * b2f(v0[j]);
      o1[j] += wB * b2f(v1[j]);
    }
  }
  bf16x8 s0, s1;
#pragma unroll
  for (int j = 0; j < 8; ++j) { s0[j] = f2bf(o0[j]); s1[j] = f2bf(o1[j]); }
  short* orow = out + (long)(b * N_ + i) * 1024 + c;
  *(bf16x8*)orow = s0;
  *(bf16x8*)(orow + 512) = s1;
}

// ---------------- host orchestration ----------------

extern "C" void kernel_launch(void* const* d_in, const int* in_sizes, int n_in,
                              void* d_out, int out_size, void* d_ws,
                              size_t ws_size, hipStream_t stream) {
  const float* x = (const float*)d_in[0];
  const float* boy = (const float*)d_in[5];
  const float* box = (const float*)d_in[10];

  char* pw = (char*)d_ws;
  auto alloc = [&](size_t n) {
    char* r = pw;
    pw += (n + 255) & ~(size_t)255;
    return r;
  };
  short* xbf   = (short*)alloc((size_t)B_ * N_ * 1024 * 2);
  // QKVx slot doubles as XQKVy until level-0 attn done; KVy contiguous after.
  short* QKVx  = (short*)alloc((size_t)B_ * N_ * 3072 * 2);
  short* KVy   = (short*)alloc((size_t)B_ * NY * 2048 * 2);
  short* QKVp  = (short*)alloc((size_t)B_ * NY * 3072 * 2);
  short* KVc   = (short*)alloc((size_t)B_ * 4096 * 2048 * 2);
  short* ao    = (short*)alloc((size_t)B_ * NY * 1024 * 2);
  short* aout  = (short*)alloc((size_t)B_ * N_ * 1024 * 2);
  short* wts   = (short*)alloc((size_t)8 * 1048576 * 2);
  short* woyT  = (short*)alloc((size_t)1048576 * 2);
  short* mkmv  = (short*)alloc((size_t)2 * 1048576 * 2);
  float* cbias = (float*)alloc((size_t)2048 * 4);
  float* part  = (float*)KVc;   // alias: time-disjoint with bf16 KVc use
  short* XQ    = QKVx;          // alias: XQKVy lives in the QKVx slot early

  CvtArgs ca;
  ca.x = x;
  ca.w[0] = (const float*)d_in[1];  // Wq_y
  ca.w[1] = (const float*)d_in[2];  // Wk_y
  ca.w[2] = (const float*)d_in[3];  // Wv_y
  ca.w[3] = (const float*)d_in[6];  // Wq_x
  ca.w[4] = (const float*)d_in[7];  // Wk_x
  ca.w[5] = (const float*)d_in[8];  // Wv_x
  ca.w[6] = (const float*)d_in[4];  // Wo_y
  ca.w[7] = (const float*)d_in[9];  // Wo_x
  ca.woy = (const float*)d_in[4];
  ca.wkx = (const float*)d_in[7];
  ca.wvx = (const float*)d_in[8];
  ca.boy = boy;
  ca.xbf = xbf;
  ca.wts = wts;
  ca.woyT = woyT;
  ca.cbias = cbias;
  cvt_all<<<17152, 256, 0, stream>>>(ca);

  const long SX = (long)N_ * 1024, SY = (long)NY * 1024;
  short* wy  = wts;                          // [Wqy|Wky|Wvy]
  short* wkv = wts + (size_t)4 * 1048576;    // [Wkx|Wvx]
  short* wx  = wts + (size_t)3 * 1048576;    // [Wqx|Wkx|Wvx]
  short* wox = wts + (size_t)7 * 1048576;

  auto gemm = [&](const short* A, const short* W, void* C, const float* bias,
                  int Mb, int Nc, long sA, long sC, int f32o, int nb) {
    dim3 g((Mb + 127) / 128, Nc / 128, nb);
    if (f32o)
      gemm_bt<1, 1><<<g, 256, 0, stream>>>(A, W, C, bias, Mb, Nc, sA, sC);
    else if (bias)
      gemm_bt<0, 1><<<g, 256, 0, stream>>>(A, W, C, bias, Mb, Nc, sA, sC);
    else
      gemm_bt<0, 0><<<g, 256, 0, stream>>>(A, W, C, nullptr, Mb, Nc, sA, sC);
  };

  // weight fold: [Mk;Mv] = [Wkx;Wvx] @ WoyT
  gemm(wkv, woyT, mkmv, nullptr, 2048, 1024, 0, 0, 0, 1);

  // XQKVy = x @ [Wqy|Wky|Wvy]^T ; pooled tree = cascade-pooled XQKVy
  gemm(xbf, wy, XQ, nullptr, 4096, 3072, SX, (long)N_ * 3072, 0, B_);
  pool_cascade<<<B_ * 256 * 3, 256, 0, stream>>>(XQ, QKVp);
  pool_qkv_b<<<dim3(128, 3), 256, 0, stream>>>(QKVp);

  // level 0: children K/V are XQKVy x-rows (stride 3072, K at +1024)
  attn_level<<<(B_ * 2048) / 4, 256, 0, stream>>>(QKVp, XQ + 1024, 3072, ao,
                                                  2048, 0, 11);

  int offl = 0, pcl = 2048;
  for (int l = 1; l < 12; ++l) {
    int offprev = offl;
    offl += pcl;
    pcl >>= 1;
    int cc = pcl * 2;
    const short* prev = ao + (long)offprev * 1024;
    int blocks = (B_ * pcl + 3) / 4;
    if (cc == 1024) {        // level 2: split-K=2 (part = 33.5 MB cap)
      dim3 g((cc / 128) * 16, 2, B_);
      gemm_sk<16><<<g, 256, 0, stream>>>(prev, wy + 1048576, part, cc, SY);
      attn_level_sk<2><<<blocks, 256, 0, stream>>>(QKVp, part, ao, pcl, offl,
                                                   11 - l);
    } else if (cc == 512) {  // level 3: split-K=4
      dim3 g((cc / 128) * 16, 4, B_);
      gemm_sk<8><<<g, 256, 0, stream>>>(prev, wy + 1048576, part, cc, SY);
      attn_level_sk<4><<<blocks, 256, 0, stream>>>(QKVp, part, ao, pcl, offl,
                                                   11 - l);
    } else if (cc <= 256) {  // levels 4..11: split-K=8 (4-step pipeline)
      dim3 g(((cc + 127) / 128) * 16, 8, B_);
      gemm_sk<4><<<g, 256, 0, stream>>>(prev, wy + 1048576, part, cc, SY);
      attn_level_sk<8><<<blocks, 256, 0, stream>>>(QKVp, part, ao, pcl, offl,
                                                   11 - l);
    } else {                 // level 1: full-K
      gemm(prev, wy + 1048576, KVc, nullptr, cc, 2048, SY, (long)cc * 2048, 0,
           B_);
      attn_level<<<blocks, 256, 0, stream>>>(QKVp, KVc, 2048, ao, pcl, offl,
                                             11 - l);
    }
  }

  // KVy = ao @ [Mk;Mv]^T + cbias ; QKVx = x @ [Wqx|Wkx|Wvx]^T
  gemm(ao, mkmv, KVy, cbias, NY, 2048, SY, (long)NY * 2048, 0, B_);
  gemm(xbf, wx, QKVx, nullptr, 4096, 3072, SX, (long)N_ * 3072, 0, B_);

  attn_final<<<(B_ * N_) / 4, 256, 0, stream>>>(QKVx, aout);

  gemm(aout, wox, d_out, box, 4096, 1024, SX, SX, 1, B_);
}

// Round 18
// 562.393 us; speedup vs baseline: 1.0257x; 1.0257x over previous
//
#include <hip/hip_runtime.h>
#include <hip/hip_bf16.h>

#define B_ 2
#define N_ 4096
#define NY 4095          // pooled tree rows per batch
#define TOT 8191

typedef __attribute__((ext_vector_type(8))) short bf16x8;
typedef __attribute__((ext_vector_type(4))) short s16x4;
typedef __attribute__((ext_vector_type(4))) float f32x4;

__device__ inline float b2f(short s) {
  unsigned u = ((unsigned)(unsigned short)s) << 16;
  float f; __builtin_memcpy(&f, &u, 4); return f;
}
__device__ inline short f2bf(float f) {
  unsigned u; __builtin_memcpy(&u, &f, 4);
  return (short)((u + 0x7fffu + ((u >> 16) & 1u)) >> 16);
}
__device__ inline float dot8(bf16x8 a, bf16x8 b) {
  float s = 0.f;
#pragma unroll
  for (int j = 0; j < 8; ++j) s += b2f(a[j]) * b2f(b[j]);
  return s;
}
__device__ inline void gl_lds16(const short* g, short* l) {
  __builtin_amdgcn_global_load_lds(
      (const __attribute__((address_space(1))) void*)g,
      (__attribute__((address_space(3))) void*)l, 16, 0, 0);
}

// ---------------- merged conversions ----------------

struct CvtArgs {
  const float* x;
  const float* w[8];
  const float* woy;
  const float* wkx;
  const float* wvx;
  const float* boy;
  short* xbf;
  short* wts;
  short* woyT;
  float* cbias;
};

__global__ __launch_bounds__(256) void cvt_all(CvtArgs a) {
  __shared__ float tile[64][65];
  int bid = blockIdx.x;
  int tid = threadIdx.x;
  if (bid < 8192) {
    long t = (((long)bid << 8) + tid) << 2;
    float4 v = *(const float4*)(a.x + t);
    s16x4 o; o.x = f2bf(v.x); o.y = f2bf(v.y); o.z = f2bf(v.z); o.w = f2bf(v.w);
    *(s16x4*)(a.xbf + t) = o;
  } else if (bid < 16384) {
    long t = (((long)(bid - 8192) << 8) + tid) << 2;
    int which = (int)(t >> 20);
    const float* sp = a.w[which] + (t & 1048575);
    float4 v = *(const float4*)sp;
    s16x4 o; o.x = f2bf(v.x); o.y = f2bf(v.y); o.z = f2bf(v.z); o.w = f2bf(v.w);
    *(s16x4*)(a.wts + t) = o;
  } else if (bid < 16640) {
    int tb = bid - 16384;
    int tr = (tb >> 4) << 6, tc = (tb & 15) << 6;
    int lc = tid & 63, lr4 = tid >> 6;
    for (int r = lr4; r < 64; r += 4)
      tile[r][lc] = a.woy[(long)(tr + r) * 1024 + tc + lc];
    __syncthreads();
    for (int r = lr4; r < 64; r += 4)
      a.woyT[(long)(tc + r) * 1024 + tr + lc] = f2bf(tile[lc][r]);
  } else {
    int f = ((bid - 16640) << 2) + (tid >> 6);
    int lane = tid & 63;
    const float* row = (f < 1024) ? (a.wkx + (long)f * 1024)
                                  : (a.wvx + (long)(f - 1024) * 1024);
    const float* rp = row + lane * 16;
    const float* bp = a.boy + lane * 16;
    float s = 0.f;
#pragma unroll
    for (int q = 0; q < 4; ++q) {
      float4 wv = *(const float4*)(rp + q * 4);
      float4 bv = *(const float4*)(bp + q * 4);
      s += wv.x * bv.x + wv.y * bv.y + wv.z * bv.z + wv.w * bv.w;
    }
#pragma unroll
    for (int sh = 32; sh >= 1; sh >>= 1) s += __shfl_xor(s, sh);
    if (lane == 0) a.cbias[f] = s;
  }
}

// ---------------- cascade pooling of projected tree (levels 0..3) --------

__global__ __launch_bounds__(256) void pool_cascade(const short* __restrict__ XQ,
                                                    short* __restrict__ QKVp) {
  int bid = blockIdx.x;
  int b = bid / 768;
  int r = bid - b * 768;
  int j16 = r / 3;
  int cb = r - j16 * 3;
  int c = cb * 1024 + threadIdx.x * 4;
  const short* src = XQ + ((long)(b * N_ + j16 * 16)) * 3072 + c;
  short* dstb = QKVp + (long)b * NY * 3072 + c;

  float l1h[4], l2h[4], l3h[4];
#pragma unroll
  for (int p = 0; p < 8; ++p) {
    s16x4 ra = *(const s16x4*)(src + (long)(2 * p) * 3072);
    s16x4 rb = *(const s16x4*)(src + (long)(2 * p + 1) * 3072);
    float l0[4];
    s16x4 o;
#pragma unroll
    for (int j = 0; j < 4; ++j) {
      l0[j] = 0.5f * (b2f(ra[j]) + b2f(rb[j]));
      o[j] = f2bf(l0[j]);
    }
    *(s16x4*)(dstb + (long)(j16 * 8 + p) * 3072) = o;
    if ((p & 1) == 0) {
#pragma unroll
      for (int j = 0; j < 4; ++j) l1h[j] = l0[j];
    } else {
      float l1[4];
      s16x4 o1;
#pragma unroll
      for (int j = 0; j < 4; ++j) {
        l1[j] = 0.5f * (l1h[j] + l0[j]);
        o1[j] = f2bf(l1[j]);
      }
      *(s16x4*)(dstb + (long)(2048 + j16 * 4 + (p >> 1)) * 3072) = o1;
      if (((p >> 1) & 1) == 0) {
#pragma unroll
        for (int j = 0; j < 4; ++j) l2h[j] = l1[j];
      } else {
        float l2[4];
        s16x4 o2;
#pragma unroll
        for (int j = 0; j < 4; ++j) {
          l2[j] = 0.5f * (l2h[j] + l1[j]);
          o2[j] = f2bf(l2[j]);
        }
        *(s16x4*)(dstb + (long)(3072 + j16 * 2 + (p >> 2)) * 3072) = o2;
        if (((p >> 2) & 1) == 0) {
#pragma unroll
          for (int j = 0; j < 4; ++j) l3h[j] = l2[j];
        } else {
          s16x4 o3;
#pragma unroll
          for (int j = 0; j < 4; ++j) o3[j] = f2bf(0.5f * (l3h[j] + l2[j]));
          *(s16x4*)(dstb + (long)(3584 + j16) * 3072) = o3;
        }
      }
    }
  }
}

// pool_qkv_b: levels 4..11 from QKVp level-3 rows (256 rows/b at off 3584)
__global__ __launch_bounds__(256) void pool_qkv_b(short* __restrict__ QKVp) {
  int wid = (blockIdx.x << 2) + (threadIdx.x >> 6);
  if (wid >= B_ * 255) return;
  int lane = threadIdx.x & 63;
  int cb = blockIdx.y << 10;
  int b = wid / 255;
  int r = wid - b * 255;
  int base = 0, size = 128, W = 2;
  while (r >= base + size) { base += size; size >>= 1; W <<= 1; }
  int j = r - base;
  const short* src = QKVp + (long)(b * NY + 3584 + j * W) * 3072 + cb + lane * 16;
  float acc[16];
#pragma unroll
  for (int c = 0; c < 16; ++c) acc[c] = 0.f;
  for (int w = 0; w < W; ++w) {
    const short* rp = src + (long)w * 3072;
    bf16x8 v0 = *(const bf16x8*)rp;
    bf16x8 v1 = *(const bf16x8*)(rp + 8);
#pragma unroll
    for (int jx = 0; jx < 8; ++jx) {
      acc[jx] += b2f(v0[jx]);
      acc[8 + jx] += b2f(v1[jx]);
    }
  }
  float sc = 1.0f / (float)W;
  bf16x8 o0, o1;
#pragma unroll
  for (int jx = 0; jx < 8; ++jx) {
    o0[jx] = f2bf(acc[jx] * sc);
    o1[jx] = f2bf(acc[8 + jx] * sc);
  }
  short* dst = QKVp + (long)(b * NY + 3840 + base + j) * 3072 + cb + lane * 16;
  *(bf16x8*)dst = o0;
  *(bf16x8*)(dst + 8) = o1;
}

// ---------------- GEMM 128x128, BK=64, XOR-swizzle, double-buffered ------

template <int STORE_F32, int HAS_BIAS>
__global__ __launch_bounds__(256) void gemm_bt(const short* __restrict__ A,
                                               const short* __restrict__ W,
                                               void* __restrict__ Cv,
                                               const float* __restrict__ bias,
                                               int Mb, int Ncols, long sA,
                                               long sC) {
  __shared__ __align__(16) short lds[32768];  // 2 bufs x (A 8K + B 8K shorts)
  const int tid = threadIdx.x;
  const int wave = tid >> 6, lane = tid & 63;
  const int row0 = blockIdx.x * 128, col0 = blockIdx.y * 128;
  const short* Ab = A + (long)blockIdx.z * sA;

  f32x4 acc[4][4];
#pragma unroll
  for (int m = 0; m < 4; ++m)
#pragma unroll
    for (int n = 0; n < 4; ++n) acc[m][n] = (f32x4){0.f, 0.f, 0.f, 0.f};

  const short* aS[4];
  const short* wS[4];
  int dBase[4];
#pragma unroll
  for (int r = 0; r < 4; ++r) {
    int P = r * 4096 + wave * 1024 + lane * 16;
    int rw = P >> 7;
    int L = P ^ ((rw & 7) << 4);
    int ks = (L & 127) >> 1;
    int ga = row0 + rw; if (ga > Mb - 1) ga = Mb - 1;
    aS[r] = Ab + ((long)ga << 10) + ks;
    wS[r] = W + ((long)(col0 + rw) << 10) + ks;
    dBase[r] = r * 2048 + wave * 512;  // shorts, wave-uniform
  }

  const int fr = lane & 15, fq = lane >> 4;
  const int wr = (wave >> 1) * 64, wc = (wave & 1) * 64;

  int offA[4][2], offB[4][2];
#pragma unroll
  for (int m = 0; m < 4; ++m)
#pragma unroll
    for (int kh = 0; kh < 2; ++kh) {
      int rwA = wr + m * 16 + fr;
      int LA = rwA * 128 + kh * 64 + fq * 16;
      offA[m][kh] = LA ^ ((rwA & 7) << 4);
      int rwB = wc + m * 16 + fr;
      int LB = rwB * 128 + kh * 64 + fq * 16;
      offB[m][kh] = LB ^ ((rwB & 7) << 4);
    }

  auto stage = [&](int kk, int buf) {
    short* lA = lds + buf * 16384;
    short* lB = lA + 8192;
#pragma unroll
    for (int r = 0; r < 4; ++r) gl_lds16(aS[r] + kk, lA + dBase[r]);
#pragma unroll
    for (int r = 0; r < 4; ++r) gl_lds16(wS[r] + kk, lB + dBase[r]);
  };
  auto compute = [&](int buf) {
    const char* bA = (const char*)(lds + buf * 16384);
    const char* bB = bA + 16384;
#pragma unroll
    for (int kh = 0; kh < 2; ++kh) {
      bf16x8 af[4], bw[4];
#pragma unroll
      for (int m = 0; m < 4; ++m)
        af[m] = *(const bf16x8*)(bA + offA[m][kh]);
#pragma unroll
      for (int n = 0; n < 4; ++n)
        bw[n] = *(const bf16x8*)(bB + offB[n][kh]);
#pragma unroll
      for (int m = 0; m < 4; ++m)
#pragma unroll
        for (int n = 0; n < 4; ++n)
          acc[m][n] = __builtin_amdgcn_mfma_f32_16x16x32_bf16(af[m], bw[n],
                                                              acc[m][n], 0, 0,
                                                              0);
    }
  };

  stage(0, 0);
  asm volatile("s_waitcnt vmcnt(0)" ::: "memory");
  __builtin_amdgcn_s_barrier();
  int cur = 0;
#pragma unroll 1
  for (int t = 0; t < 15; ++t) {
    stage((t + 1) * 64, cur ^ 1);
    compute(cur);
    asm volatile("s_waitcnt vmcnt(0)" ::: "memory");
    __builtin_amdgcn_s_barrier();
    cur ^= 1;
  }
  compute(cur);

#pragma unroll
  for (int n = 0; n < 4; ++n) {
    int col = col0 + wc + n * 16 + fr;
    float bv = HAS_BIAS ? bias[col] : 0.f;
#pragma unroll
    for (int m = 0; m < 4; ++m) {
#pragma unroll
      for (int q = 0; q < 4; ++q) {
        int row = row0 + wr + m * 16 + fq * 4 + q;
        if (row < Mb) {
          long off = (long)blockIdx.z * sC + (long)row * Ncols + col;
          float v = acc[m][n][q] + bv;
          if (STORE_F32) ((float*)Cv)[off] = v;
          else ((short*)Cv)[off] = f2bf(v);
        }
      }
    }
  }
}

// ---------------- split-K chain GEMM (latency-optimized) ----------------

template <int KSTEPS>
__global__ __launch_bounds__(256) void gemm_sk(const short* __restrict__ A,
                                               const short* __restrict__ W,
                                               float* __restrict__ part,
                                               int Mrows, long sA) {
  __shared__ __align__(16) short lds[32768];
  const int tid = threadIdx.x;
  const int wave = tid >> 6, lane = tid & 63;
  const int mt = blockIdx.x >> 4, nt = blockIdx.x & 15;
  const int ks = blockIdx.y;
  const int KSPLIT = 32 / KSTEPS;
  const int row0 = mt * 128, col0 = nt * 128;
  const short* Ab = A + (long)blockIdx.z * sA;

  f32x4 acc[4][4];
#pragma unroll
  for (int m = 0; m < 4; ++m)
#pragma unroll
    for (int n = 0; n < 4; ++n) acc[m][n] = (f32x4){0.f, 0.f, 0.f, 0.f};

  const int sr = lane >> 2;
  const int sk = (lane & 3) * 8;
  const int ra0 = wave * 32 + sr;
  const int ra1 = ra0 + 16;
  const int ga0 = (row0 + ra0 < Mrows) ? (row0 + ra0) : (Mrows - 1);
  const int ga1 = (row0 + ra1 < Mrows) ? (row0 + ra1) : (Mrows - 1);
  const long kbase = (long)ks * KSTEPS * 32;
  const short* aP0 = Ab + ((long)ga0 << 10) + kbase + sk;
  const short* aP1 = Ab + ((long)ga1 << 10) + kbase + sk;
  const short* wP0 = W + ((long)(col0 + ra0) << 10) + kbase + sk;
  const short* wP1 = W + ((long)(col0 + ra1) << 10) + kbase + sk;
  const int dA0 = (wave * 2 + 0) * 512, dA1 = (wave * 2 + 1) * 512;
  const int dB0 = 4096 + dA0, dB1 = 4096 + dA1;

  const int fr = lane & 15, fq = lane >> 4;
  const int wr = (wave >> 1) * 64, wc = (wave & 1) * 64;

  auto stage = [&](int kt) {
    short* sb = lds + (kt & 3) * 8192;
    const long ko = (long)kt * 32;
    gl_lds16(aP0 + ko, sb + dA0);
    gl_lds16(aP1 + ko, sb + dA1);
    gl_lds16(wP0 + ko, sb + dB0);
    gl_lds16(wP1 + ko, sb + dB1);
  };
  auto compute = [&](int s) {
    const short* bA = lds + s * 8192;
    const short* bB = bA + 4096;
    bf16x8 af[4], bw[4];
#pragma unroll
    for (int m = 0; m < 4; ++m)
      af[m] = *(const bf16x8*)&bA[(wr + m * 16 + fr) * 32 + fq * 8];
#pragma unroll
    for (int n = 0; n < 4; ++n)
      bw[n] = *(const bf16x8*)&bB[(wc + n * 16 + fr) * 32 + fq * 8];
#pragma unroll
    for (int m = 0; m < 4; ++m)
#pragma unroll
      for (int n = 0; n < 4; ++n)
        acc[m][n] = __builtin_amdgcn_mfma_f32_16x16x32_bf16(af[m], bw[n],
                                                            acc[m][n], 0, 0, 0);
  };

  stage(0); stage(1); stage(2);
#pragma unroll 1
  for (int j = 0; j + 4 <= KSTEPS; ++j) {
    asm volatile("s_waitcnt vmcnt(8)" ::: "memory");
    __builtin_amdgcn_s_barrier();
    compute(j & 3);
    stage(j + 3);
  }
  asm volatile("s_waitcnt vmcnt(8)" ::: "memory");
  __builtin_amdgcn_s_barrier();
  compute((KSTEPS - 3) & 3);
  asm volatile("s_waitcnt vmcnt(4)" ::: "memory");
  __builtin_amdgcn_s_barrier();
  compute((KSTEPS - 2) & 3);
  asm volatile("s_waitcnt vmcnt(0)" ::: "memory");
  __builtin_amdgcn_s_barrier();
  compute((KSTEPS - 1) & 3);

  float* pb = part + ((long)(blockIdx.z * KSPLIT + ks) * Mrows) * 2048;
#pragma unroll
  for (int n = 0; n < 4; ++n) {
    int col = col0 + wc + n * 16 + fr;
#pragma unroll
    for (int m = 0; m < 4; ++m) {
#pragma unroll
      for (int q = 0; q < 4; ++q) {
        int row = row0 + wr + m * 16 + fq * 4 + q;
        if (row < Mrows) pb[(long)row * 2048 + col] = acc[m][n][q];
      }
    }
  }
}

// ---------------- per-level 3-key attention (bf16 children) -------------

__global__ __launch_bounds__(256) void attn_level(
    const short* __restrict__ QKVp, const short* __restrict__ childK, int cs,
    short* __restrict__ ao, int pc, int off, int lgpc) {
  int wid = (blockIdx.x << 2) + (threadIdx.x >> 6);
  if (wid >= B_ * pc) return;
  int lane = threadIdx.x & 63;
  int b = wid >> lgpc;
  int p = wid & (pc - 1);
  int c = lane * 8;
  const short* prow = QKVp + (long)(b * NY + off + p) * 3072 + c;
  const short* c0r = childK + (long)((b * pc + p) * 2) * cs + c;
  const short* c1r = c0r + cs;
  bf16x8 q0 = *(const bf16x8*)(prow);
  bf16x8 q1 = *(const bf16x8*)(prow + 512);
  bf16x8 kp0 = *(const bf16x8*)(prow + 1024);
  bf16x8 kp1 = *(const bf16x8*)(prow + 1536);
  bf16x8 ka0 = *(const bf16x8*)(c0r);
  bf16x8 ka1 = *(const bf16x8*)(c0r + 512);
  bf16x8 kb0 = *(const bf16x8*)(c1r);
  bf16x8 kb1 = *(const bf16x8*)(c1r + 512);
  float d0 = dot8(q0, kp0), d1 = dot8(q1, kp1);
  float d2 = dot8(q0, ka0), d3 = dot8(q1, ka1);
  float d4 = dot8(q0, kb0), d5 = dot8(q1, kb1);
#pragma unroll
  for (int s = 1; s <= 4; s <<= 1) {
    d0 += __shfl_xor(d0, s); d1 += __shfl_xor(d1, s);
    d2 += __shfl_xor(d2, s); d3 += __shfl_xor(d3, s);
    d4 += __shfl_xor(d4, s); d5 += __shfl_xor(d5, s);
  }
  d0 *= 0.125f; d1 *= 0.125f; d2 *= 0.125f;
  d3 *= 0.125f; d4 *= 0.125f; d5 *= 0.125f;
  float mA = fmaxf(d0, fmaxf(d2, d4));
  float e0 = __expf(d0 - mA), e2 = __expf(d2 - mA), e4 = __expf(d4 - mA);
  float iA = 1.f / (e0 + e2 + e4);
  e0 *= iA; e2 *= iA; e4 *= iA;
  float mB = fmaxf(d1, fmaxf(d3, d5));
  float e1 = __expf(d1 - mB), e3 = __expf(d3 - mB), e5 = __expf(d5 - mB);
  float iB = 1.f / (e1 + e3 + e5);
  e1 *= iB; e3 *= iB; e5 *= iB;
  bf16x8 vp0 = *(const bf16x8*)(prow + 2048);
  bf16x8 vp1 = *(const bf16x8*)(prow + 2560);
  bf16x8 va0 = *(const bf16x8*)(c0r + 1024);
  bf16x8 va1 = *(const bf16x8*)(c0r + 1536);
  bf16x8 vb0 = *(const bf16x8*)(c1r + 1024);
  bf16x8 vb1 = *(const bf16x8*)(c1r + 1536);
  bf16x8 s0, s1;
#pragma unroll
  for (int j = 0; j < 8; ++j) {
    s0[j] = f2bf(e0 * b2f(vp0[j]) + e2 * b2f(va0[j]) + e4 * b2f(vb0[j]));
    s1[j] = f2bf(e1 * b2f(vp1[j]) + e3 * b2f(va1[j]) + e5 * b2f(vb1[j]));
  }
  short* orow = ao + (long)(b * NY + off + p) * 1024 + c;
  *(bf16x8*)orow = s0;
  *(bf16x8*)(orow + 512) = s1;
}

// ---------------- per-level 3-key attention (f32 split-K partials) -------

template <int KS>
__device__ __forceinline__ void load8sum(const float* p, long kstride,
                                         float* o) {
  float4 a = *(const float4*)p, b = *(const float4*)(p + 4);
  o[0] = a.x; o[1] = a.y; o[2] = a.z; o[3] = a.w;
  o[4] = b.x; o[5] = b.y; o[6] = b.z; o[7] = b.w;
#pragma unroll
  for (int ks = 1; ks < KS; ++ks) {
    const float* q = p + ks * kstride;
    float4 c = *(const float4*)q, d = *(const float4*)(q + 4);
    o[0] += c.x; o[1] += c.y; o[2] += c.z; o[3] += c.w;
    o[4] += d.x; o[5] += d.y; o[6] += d.z; o[7] += d.w;
  }
}
__device__ __forceinline__ float dot8f(bf16x8 a, const float* b) {
  float s = 0.f;
#pragma unroll
  for (int j = 0; j < 8; ++j) s += b2f(a[j]) * b[j];
  return s;
}

template <int KS>
__global__ __launch_bounds__(256) void attn_level_sk(
    const short* __restrict__ QKVp, const float* __restrict__ part,
    short* __restrict__ ao, int pc, int off, int lgpc) {
  int wid = (blockIdx.x << 2) + (threadIdx.x >> 6);
  if (wid >= B_ * pc) return;
  int lane = threadIdx.x & 63;
  int b = wid >> lgpc;
  int p = wid & (pc - 1);
  int c = lane * 8;
  const int cc = pc * 2;
  const long kstride = (long)cc * 2048;
  const short* prow = QKVp + (long)(b * NY + off + p) * 3072 + c;
  const float* c0r = part + (long)(b * KS) * kstride + (long)(p * 2) * 2048 + c;
  const float* c1r = c0r + 2048;
  bf16x8 q0 = *(const bf16x8*)(prow);
  bf16x8 q1 = *(const bf16x8*)(prow + 512);
  bf16x8 kp0 = *(const bf16x8*)(prow + 1024);
  bf16x8 kp1 = *(const bf16x8*)(prow + 1536);
  float ka0[8], ka1[8], kb0[8], kb1[8];
  load8sum<KS>(c0r, kstride, ka0);
  load8sum<KS>(c0r + 512, kstride, ka1);
  load8sum<KS>(c1r, kstride, kb0);
  load8sum<KS>(c1r + 512, kstride, kb1);
  float d0 = dot8(q0, kp0), d1 = dot8(q1, kp1);
  float d2 = dot8f(q0, ka0), d3 = dot8f(q1, ka1);
  float d4 = dot8f(q0, kb0), d5 = dot8f(q1, kb1);
#pragma unroll
  for (int s = 1; s <= 4; s <<= 1) {
    d0 += __shfl_xor(d0, s); d1 += __shfl_xor(d1, s);
    d2 += __shfl_xor(d2, s); d3 += __shfl_xor(d3, s);
    d4 += __shfl_xor(d4, s); d5 += __shfl_xor(d5, s);
  }
  d0 *= 0.125f; d1 *= 0.125f; d2 *= 0.125f;
  d3 *= 0.125f; d4 *= 0.125f; d5 *= 0.125f;
  float mA = fmaxf(d0, fmaxf(d2, d4));
  float e0 = __expf(d0 - mA), e2 = __expf(d2 - mA), e4 = __expf(d4 - mA);
  float iA = 1.f / (e0 + e2 + e4);
  e0 *= iA; e2 *= iA; e4 *= iA;
  float mB = fmaxf(d1, fmaxf(d3, d5));
  float e1 = __expf(d1 - mB), e3 = __expf(d3 - mB), e5 = __expf(d5 - mB);
  float iB = 1.f / (e1 + e3 + e5);
  e1 *= iB; e3 *= iB; e5 *= iB;
  bf16x8 vp0 = *(const bf16x8*)(prow + 2048);
  bf16x8 vp1 = *(const bf16x8*)(prow + 2560);
  float va0[8], va1[8], vb0[8], vb1[8];
  load8sum<KS>(c0r + 1024, kstride, va0);
  load8sum<KS>(c0r + 1536, kstride, va1);
  load8sum<KS>(c1r + 1024, kstride, vb0);
  load8sum<KS>(c1r + 1536, kstride, vb1);
  bf16x8 s0, s1;
#pragma unroll
  for (int j = 0; j < 8; ++j) {
    s0[j] = f2bf(e0 * b2f(vp0[j]) + e2 * va0[j] + e4 * vb0[j]);
    s1[j] = f2bf(e1 * b2f(vp1[j]) + e3 * va1[j] + e5 * vb1[j]);
  }
  short* orow = ao + (long)(b * NY + off + p) * 1024 + c;
  *(bf16x8*)orow = s0;
  *(bf16x8*)(orow + 512) = s1;
}

// ---------------- final 13-key sparse attention ----------------

__global__ __launch_bounds__(256) void attn_final(const short* __restrict__ QKVx,
                                                  short* __restrict__ out) {
  const long XLEN = (long)B_ * N_ * 3072;
  int wid = (blockIdx.x << 2) + (threadIdx.x >> 6);
  int lane = threadIdx.x & 63;
  int b = wid >> 12;
  int i = wid & (N_ - 1);
  int c = lane * 8;
  const short* qrow = QKVx + (long)(b * N_ + i) * 3072;
  bf16x8 q0 = *(const bf16x8*)(qrow + c);
  bf16x8 q1 = *(const bf16x8*)(qrow + 512 + c);

  long offs[13];
  unsigned mbits = 0;
  offs[0] = (long)(b * N_ + i) * 3072 + 1024;
  int ncur = i;
#pragma unroll
  for (int lvl = 0; lvl < 12; ++lvl) {
    int pair, nx;
    if (lvl == 0) { pair = ncur; nx = ncur ^ 1; }
    else { pair = (ncur >> 1) + N_; nx = pair ^ 1; }
    bool valid = nx <= 2 * N_ - 3;
    int r = valid ? nx : (2 * N_ - 2);
    if (valid && pair < nx) mbits |= 1u << (lvl + 1);
    offs[lvl + 1] = (r < N_) ? ((long)(b * N_ + r) * 3072 + 1024)
                             : (XLEN + (long)(b * NY + (r - N_)) * 2048);
    ncur = nx;
  }
  float dA[13], dB[13];
#pragma unroll
  for (int k = 0; k < 13; ++k) {
    const short* kb = QKVx + offs[k];
    dA[k] = dot8(q0, *(const bf16x8*)(kb + c));
    dB[k] = dot8(q1, *(const bf16x8*)(kb + 512 + c));
  }
#pragma unroll
  for (int s = 1; s <= 4; s <<= 1) {
#pragma unroll
    for (int k = 0; k < 13; ++k) {
      dA[k] += __shfl_xor(dA[k], s);
      dB[k] += __shfl_xor(dB[k], s);
    }
  }
  float mA = -1e30f, mB = -1e30f;
#pragma unroll
  for (int k = 0; k < 13; ++k) {
    bool msk = (mbits >> k) & 1;
    dA[k] = msk ? -1e30f : dA[k] * 0.125f;
    dB[k] = msk ? -1e30f : dB[k] * 0.125f;
    mA = fmaxf(mA, dA[k]);
    mB = fmaxf(mB, dB[k]);
  }
  float sA = 0.f, sB = 0.f;
#pragma unroll
  for (int k = 0; k < 13; ++k) {
    dA[k] = __expf(dA[k] - mA); sA += dA[k];
    dB[k] = __expf(dB[k] - mB); sB += dB[k];
  }
  float iA = 1.f / sA, iB = 1.f / sB;
  float o0[8] = {0, 0, 0, 0, 0, 0, 0, 0};
  float o1[8] = {0, 0, 0, 0, 0, 0, 0, 0};
#pragma unroll
  for (int k = 0; k < 13; ++k) {
    const short* vb = QKVx + offs[k] + 1024;
    bf16x8 v0 = *(const bf16x8*)(vb + c);
    bf16x8 v1 = *(const bf16x8*)(vb + 512 + c);
    float wA = dA[k] * iA, wB = dB[k] * iB;
#pragma unroll
    for (int j = 0; j < 8; ++j) {
      o0[j] += wA * b2f(v0[j]);
      o1[j] += wB * b2f(v1[j]);
    }
  }
  bf16x8 s0, s1;
#pragma unroll
  for (int j = 0; j < 8; ++j) { s0[j] = f2bf(o0[j]); s1[j] = f2bf(o1[j]); }
  short* orow = out + (long)(b * N_ + i) * 1024 + c;
  *(bf16x8*)orow = s0;
  *(bf16x8*)(orow + 512) = s1;
}

// ---------------- host orchestration ----------------

extern "C" void kernel_launch(void* const* d_in, const int* in_sizes, int n_in,
                              void* d_out, int out_size, void* d_ws,
                              size_t ws_size, hipStream_t stream) {
  const float* x = (const float*)d_in[0];
  const float* boy = (const float*)d_in[5];
  const float* box = (const float*)d_in[10];

  char* pw = (char*)d_ws;
  auto alloc = [&](size_t n) {
    char* r = pw;
    pw += (n + 255) & ~(size_t)255;
    return r;
  };
  short* xbf   = (short*)alloc((size_t)B_ * N_ * 1024 * 2);
  // QKVx slot doubles as XQKVy until level-0 attn done; KVy contiguous after.
  short* QKVx  = (short*)alloc((size_t)B_ * N_ * 3072 * 2);
  short* KVy   = (short*)alloc((size_t)B_ * NY * 2048 * 2);
  short* QKVp  = (short*)alloc((size_t)B_ * NY * 3072 * 2);
  short* KVc   = (short*)alloc((size_t)B_ * 4096 * 2048 * 2);
  short* ao    = (short*)alloc((size_t)B_ * NY * 1024 * 2);
  short* aout  = (short*)alloc((size_t)B_ * N_ * 1024 * 2);
  short* wts   = (short*)alloc((size_t)8 * 1048576 * 2);
  short* woyT  = (short*)alloc((size_t)1048576 * 2);
  short* mkmv  = (short*)alloc((size_t)2 * 1048576 * 2);
  float* cbias = (float*)alloc((size_t)2048 * 4);
  float* part  = (float*)KVc;   // alias: time-disjoint with bf16 KVc use
  short* XQ    = QKVx;          // alias: XQKVy lives in the QKVx slot early

  CvtArgs ca;
  ca.x = x;
  ca.w[0] = (const float*)d_in[1];  // Wq_y
  ca.w[1] = (const float*)d_in[2];  // Wk_y
  ca.w[2] = (const float*)d_in[3];  // Wv_y
  ca.w[3] = (const float*)d_in[6];  // Wq_x
  ca.w[4] = (const float*)d_in[7];  // Wk_x
  ca.w[5] = (const float*)d_in[8];  // Wv_x
  ca.w[6] = (const float*)d_in[4];  // Wo_y
  ca.w[7] = (const float*)d_in[9];  // Wo_x
  ca.woy = (const float*)d_in[4];
  ca.wkx = (const float*)d_in[7];
  ca.wvx = (const float*)d_in[8];
  ca.boy = boy;
  ca.xbf = xbf;
  ca.wts = wts;
  ca.woyT = woyT;
  ca.cbias = cbias;
  cvt_all<<<17152, 256, 0, stream>>>(ca);

  const long SX = (long)N_ * 1024, SY = (long)NY * 1024;
  short* wy  = wts;                          // [Wqy|Wky|Wvy]
  short* wkv = wts + (size_t)4 * 1048576;    // [Wkx|Wvx]
  short* wx  = wts + (size_t)3 * 1048576;    // [Wqx|Wkx|Wvx]
  short* wox = wts + (size_t)7 * 1048576;

  auto gemm = [&](const short* A, const short* W, void* C, const float* bias,
                  int Mb, int Nc, long sA, long sC, int f32o, int nb) {
    dim3 g((Mb + 127) / 128, Nc / 128, nb);
    if (f32o)
      gemm_bt<1, 1><<<g, 256, 0, stream>>>(A, W, C, bias, Mb, Nc, sA, sC);
    else if (bias)
      gemm_bt<0, 1><<<g, 256, 0, stream>>>(A, W, C, bias, Mb, Nc, sA, sC);
    else
      gemm_bt<0, 0><<<g, 256, 0, stream>>>(A, W, C, nullptr, Mb, Nc, sA, sC);
  };

  // weight fold: [Mk;Mv] = [Wkx;Wvx] @ WoyT
  gemm(wkv, woyT, mkmv, nullptr, 2048, 1024, 0, 0, 0, 1);

  // XQKVy = x @ [Wqy|Wky|Wvy]^T ; pooled tree = cascade-pooled XQKVy
  gemm(xbf, wy, XQ, nullptr, 4096, 3072, SX, (long)N_ * 3072, 0, B_);
  pool_cascade<<<B_ * 256 * 3, 256, 0, stream>>>(XQ, QKVp);
  pool_qkv_b<<<dim3(128, 3), 256, 0, stream>>>(QKVp);

  // level 0: children K/V are XQKVy x-rows (stride 3072, K at +1024)
  attn_level<<<(B_ * 2048) / 4, 256, 0, stream>>>(QKVp, XQ + 1024, 3072, ao,
                                                  2048, 0, 11);

  int offl = 0, pcl = 2048;
  for (int l = 1; l < 12; ++l) {
    int offprev = offl;
    offl += pcl;
    pcl >>= 1;
    int cc = pcl * 2;
    const short* prev = ao + (long)offprev * 1024;
    int blocks = (B_ * pcl + 3) / 4;
    if (cc == 1024) {        // level 2: split-K=2
      dim3 g((cc / 128) * 16, 2, B_);
      gemm_sk<16><<<g, 256, 0, stream>>>(prev, wy + 1048576, part, cc, SY);
      attn_level_sk<2><<<blocks, 256, 0, stream>>>(QKVp, part, ao, pcl, offl,
                                                   11 - l);
    } else if (cc <= 512) {  // levels 3..11: split-K=4
      dim3 g(((cc + 127) / 128) * 16, 4, B_);
      gemm_sk<8><<<g, 256, 0, stream>>>(prev, wy + 1048576, part, cc, SY);
      attn_level_sk<4><<<blocks, 256, 0, stream>>>(QKVp, part, ao, pcl, offl,
                                                   11 - l);
    } else {                 // level 1: full-K
      gemm(prev, wy + 1048576, KVc, nullptr, cc, 2048, SY, (long)cc * 2048, 0,
           B_);
      attn_level<<<blocks, 256, 0, stream>>>(QKVp, KVc, 2048, ao, pcl, offl,
                                             11 - l);
    }
  }

  // KVy = ao @ [Mk;Mv]^T + cbias ; QKVx = x @ [Wqx|Wkx|Wvx]^T
  gemm(ao, mkmv, KVy, cbias, NY, 2048, SY, (long)NY * 2048, 0, B_);
  gemm(xbf, wx, QKVx, nullptr, 4096, 3072, SX, (long)N_ * 3072, 0, B_);

  attn_final<<<(B_ * N_) / 4, 256, 0, stream>>>(QKVx, aout);

  gemm(aout, wox, d_out, box, 4096, 1024, SX, SX, 1, B_);
}

// Round 19
// 559.920 us; speedup vs baseline: 1.0303x; 1.0044x over previous
//
#include <hip/hip_runtime.h>
#include <hip/hip_bf16.h>

#define B_ 2
#define N_ 4096
#define NY 4095          // pooled tree rows per batch
#define TOT 8191

typedef __attribute__((ext_vector_type(8))) short bf16x8;
typedef __attribute__((ext_vector_type(4))) short s16x4;
typedef __attribute__((ext_vector_type(4))) float f32x4;

__device__ inline float b2f(short s) {
  unsigned u = ((unsigned)(unsigned short)s) << 16;
  float f; __builtin_memcpy(&f, &u, 4); return f;
}
__device__ inline short f2bf(float f) {
  unsigned u; __builtin_memcpy(&u, &f, 4);
  return (short)((u + 0x7fffu + ((u >> 16) & 1u)) >> 16);
}
__device__ inline float dot8(bf16x8 a, bf16x8 b) {
  float s = 0.f;
#pragma unroll
  for (int j = 0; j < 8; ++j) s += b2f(a[j]) * b2f(b[j]);
  return s;
}
__device__ inline void gl_lds16(const short* g, short* l) {
  __builtin_amdgcn_global_load_lds(
      (const __attribute__((address_space(1))) void*)g,
      (__attribute__((address_space(3))) void*)l, 16, 0, 0);
}

// ---------------- merged conversions ----------------

struct CvtArgs {
  const float* x;
  const float* w[8];
  const float* woy;
  const float* wkx;
  const float* wvx;
  const float* boy;
  short* xbf;
  short* wts;
  short* woyT;
  float* cbias;
};

__global__ __launch_bounds__(256) void cvt_all(CvtArgs a) {
  __shared__ float tile[64][65];
  int bid = blockIdx.x;
  int tid = threadIdx.x;
  if (bid < 8192) {
    long t = (((long)bid << 8) + tid) << 2;
    float4 v = *(const float4*)(a.x + t);
    s16x4 o; o.x = f2bf(v.x); o.y = f2bf(v.y); o.z = f2bf(v.z); o.w = f2bf(v.w);
    *(s16x4*)(a.xbf + t) = o;
  } else if (bid < 16384) {
    long t = (((long)(bid - 8192) << 8) + tid) << 2;
    int which = (int)(t >> 20);
    const float* sp = a.w[which] + (t & 1048575);
    float4 v = *(const float4*)sp;
    s16x4 o; o.x = f2bf(v.x); o.y = f2bf(v.y); o.z = f2bf(v.z); o.w = f2bf(v.w);
    *(s16x4*)(a.wts + t) = o;
  } else if (bid < 16640) {
    int tb = bid - 16384;
    int tr = (tb >> 4) << 6, tc = (tb & 15) << 6;
    int lc = tid & 63, lr4 = tid >> 6;
    for (int r = lr4; r < 64; r += 4)
      tile[r][lc] = a.woy[(long)(tr + r) * 1024 + tc + lc];
    __syncthreads();
    for (int r = lr4; r < 64; r += 4)
      a.woyT[(long)(tc + r) * 1024 + tr + lc] = f2bf(tile[lc][r]);
  } else {
    int f = ((bid - 16640) << 2) + (tid >> 6);
    int lane = tid & 63;
    const float* row = (f < 1024) ? (a.wkx + (long)f * 1024)
                                  : (a.wvx + (long)(f - 1024) * 1024);
    const float* rp = row + lane * 16;
    const float* bp = a.boy + lane * 16;
    float s = 0.f;
#pragma unroll
    for (int q = 0; q < 4; ++q) {
      float4 wv = *(const float4*)(rp + q * 4);
      float4 bv = *(const float4*)(bp + q * 4);
      s += wv.x * bv.x + wv.y * bv.y + wv.z * bv.z + wv.w * bv.w;
    }
#pragma unroll
    for (int sh = 32; sh >= 1; sh >>= 1) s += __shfl_xor(s, sh);
    if (lane == 0) a.cbias[f] = s;
  }
}

// ---------------- cascade pooling of projected tree (levels 0..3) --------

__global__ __launch_bounds__(256) void pool_cascade(const short* __restrict__ XQ,
                                                    short* __restrict__ QKVp) {
  int bid = blockIdx.x;
  int b = bid / 768;
  int r = bid - b * 768;
  int j16 = r / 3;
  int cb = r - j16 * 3;
  int c = cb * 1024 + threadIdx.x * 4;
  const short* src = XQ + ((long)(b * N_ + j16 * 16)) * 3072 + c;
  short* dstb = QKVp + (long)b * NY * 3072 + c;

  float l1h[4], l2h[4], l3h[4];
#pragma unroll
  for (int p = 0; p < 8; ++p) {
    s16x4 ra = *(const s16x4*)(src + (long)(2 * p) * 3072);
    s16x4 rb = *(const s16x4*)(src + (long)(2 * p + 1) * 3072);
    float l0[4];
    s16x4 o;
#pragma unroll
    for (int j = 0; j < 4; ++j) {
      l0[j] = 0.5f * (b2f(ra[j]) + b2f(rb[j]));
      o[j] = f2bf(l0[j]);
    }
    *(s16x4*)(dstb + (long)(j16 * 8 + p) * 3072) = o;
    if ((p & 1) == 0) {
#pragma unroll
      for (int j = 0; j < 4; ++j) l1h[j] = l0[j];
    } else {
      float l1[4];
      s16x4 o1;
#pragma unroll
      for (int j = 0; j < 4; ++j) {
        l1[j] = 0.5f * (l1h[j] + l0[j]);
        o1[j] = f2bf(l1[j]);
      }
      *(s16x4*)(dstb + (long)(2048 + j16 * 4 + (p >> 1)) * 3072) = o1;
      if (((p >> 1) & 1) == 0) {
#pragma unroll
        for (int j = 0; j < 4; ++j) l2h[j] = l1[j];
      } else {
        float l2[4];
        s16x4 o2;
#pragma unroll
        for (int j = 0; j < 4; ++j) {
          l2[j] = 0.5f * (l2h[j] + l1[j]);
          o2[j] = f2bf(l2[j]);
        }
        *(s16x4*)(dstb + (long)(3072 + j16 * 2 + (p >> 2)) * 3072) = o2;
        if (((p >> 2) & 1) == 0) {
#pragma unroll
          for (int j = 0; j < 4; ++j) l3h[j] = l2[j];
        } else {
          s16x4 o3;
#pragma unroll
          for (int j = 0; j < 4; ++j) o3[j] = f2bf(0.5f * (l3h[j] + l2[j]));
          *(s16x4*)(dstb + (long)(3584 + j16) * 3072) = o3;
        }
      }
    }
  }
}

// pool_qkv_b: levels 4..11 from QKVp level-3 rows (256 rows/b at off 3584)
__global__ __launch_bounds__(256) void pool_qkv_b(short* __restrict__ QKVp) {
  int wid = (blockIdx.x << 2) + (threadIdx.x >> 6);
  if (wid >= B_ * 255) return;
  int lane = threadIdx.x & 63;
  int cb = blockIdx.y << 10;
  int b = wid / 255;
  int r = wid - b * 255;
  int base = 0, size = 128, W = 2;
  while (r >= base + size) { base += size; size >>= 1; W <<= 1; }
  int j = r - base;
  const short* src = QKVp + (long)(b * NY + 3584 + j * W) * 3072 + cb + lane * 16;
  float acc[16];
#pragma unroll
  for (int c = 0; c < 16; ++c) acc[c] = 0.f;
  for (int w = 0; w < W; ++w) {
    const short* rp = src + (long)w * 3072;
    bf16x8 v0 = *(const bf16x8*)rp;
    bf16x8 v1 = *(const bf16x8*)(rp + 8);
#pragma unroll
    for (int jx = 0; jx < 8; ++jx) {
      acc[jx] += b2f(v0[jx]);
      acc[8 + jx] += b2f(v1[jx]);
    }
  }
  float sc = 1.0f / (float)W;
  bf16x8 o0, o1;
#pragma unroll
  for (int jx = 0; jx < 8; ++jx) {
    o0[jx] = f2bf(acc[jx] * sc);
    o1[jx] = f2bf(acc[8 + jx] * sc);
  }
  short* dst = QKVp + (long)(b * NY + 3840 + base + j) * 3072 + cb + lane * 16;
  *(bf16x8*)dst = o0;
  *(bf16x8*)(dst + 8) = o1;
}

// ---------------- GEMM 128x128, BK=64, XOR-swizzle, double-buffered ------

template <int STORE_F32, int HAS_BIAS>
__global__ __launch_bounds__(256) void gemm_bt(const short* __restrict__ A,
                                               const short* __restrict__ W,
                                               void* __restrict__ Cv,
                                               const float* __restrict__ bias,
                                               int Mb, int Ncols, long sA,
                                               long sC) {
  __shared__ __align__(16) short lds[32768];  // 2 bufs x (A 8K + B 8K shorts)
  const int tid = threadIdx.x;
  const int wave = tid >> 6, lane = tid & 63;
  const int row0 = blockIdx.x * 128, col0 = blockIdx.y * 128;
  const short* Ab = A + (long)blockIdx.z * sA;

  f32x4 acc[4][4];
#pragma unroll
  for (int m = 0; m < 4; ++m)
#pragma unroll
    for (int n = 0; n < 4; ++n) acc[m][n] = (f32x4){0.f, 0.f, 0.f, 0.f};

  const short* aS[4];
  const short* wS[4];
  int dBase[4];
#pragma unroll
  for (int r = 0; r < 4; ++r) {
    int P = r * 4096 + wave * 1024 + lane * 16;
    int rw = P >> 7;
    int L = P ^ ((rw & 7) << 4);
    int ks = (L & 127) >> 1;
    int ga = row0 + rw; if (ga > Mb - 1) ga = Mb - 1;
    aS[r] = Ab + ((long)ga << 10) + ks;
    wS[r] = W + ((long)(col0 + rw) << 10) + ks;
    dBase[r] = r * 2048 + wave * 512;  // shorts, wave-uniform
  }

  const int fr = lane & 15, fq = lane >> 4;
  const int wr = (wave >> 1) * 64, wc = (wave & 1) * 64;

  int offA[4][2], offB[4][2];
#pragma unroll
  for (int m = 0; m < 4; ++m)
#pragma unroll
    for (int kh = 0; kh < 2; ++kh) {
      int rwA = wr + m * 16 + fr;
      int LA = rwA * 128 + kh * 64 + fq * 16;
      offA[m][kh] = LA ^ ((rwA & 7) << 4);
      int rwB = wc + m * 16 + fr;
      int LB = rwB * 128 + kh * 64 + fq * 16;
      offB[m][kh] = LB ^ ((rwB & 7) << 4);
    }

  auto stage = [&](int kk, int buf) {
    short* lA = lds + buf * 16384;
    short* lB = lA + 8192;
#pragma unroll
    for (int r = 0; r < 4; ++r) gl_lds16(aS[r] + kk, lA + dBase[r]);
#pragma unroll
    for (int r = 0; r < 4; ++r) gl_lds16(wS[r] + kk, lB + dBase[r]);
  };
  auto compute = [&](int buf) {
    const char* bA = (const char*)(lds + buf * 16384);
    const char* bB = bA + 16384;
#pragma unroll
    for (int kh = 0; kh < 2; ++kh) {
      bf16x8 af[4], bw[4];
#pragma unroll
      for (int m = 0; m < 4; ++m)
        af[m] = *(const bf16x8*)(bA + offA[m][kh]);
#pragma unroll
      for (int n = 0; n < 4; ++n)
        bw[n] = *(const bf16x8*)(bB + offB[n][kh]);
#pragma unroll
      for (int m = 0; m < 4; ++m)
#pragma unroll
        for (int n = 0; n < 4; ++n)
          acc[m][n] = __builtin_amdgcn_mfma_f32_16x16x32_bf16(af[m], bw[n],
                                                              acc[m][n], 0, 0,
                                                              0);
    }
  };

  stage(0, 0);
  asm volatile("s_waitcnt vmcnt(0)" ::: "memory");
  __builtin_amdgcn_s_barrier();
  int cur = 0;
#pragma unroll 1
  for (int t = 0; t < 15; ++t) {
    stage((t + 1) * 64, cur ^ 1);
    compute(cur);
    asm volatile("s_waitcnt vmcnt(0)" ::: "memory");
    __builtin_amdgcn_s_barrier();
    cur ^= 1;
  }
  compute(cur);

#pragma unroll
  for (int n = 0; n < 4; ++n) {
    int col = col0 + wc + n * 16 + fr;
    float bv = HAS_BIAS ? bias[col] : 0.f;
#pragma unroll
    for (int m = 0; m < 4; ++m) {
#pragma unroll
      for (int q = 0; q < 4; ++q) {
        int row = row0 + wr + m * 16 + fq * 4 + q;
        if (row < Mb) {
          long off = (long)blockIdx.z * sC + (long)row * Ncols + col;
          float v = acc[m][n][q] + bv;
          if (STORE_F32) ((float*)Cv)[off] = v;
          else ((short*)Cv)[off] = f2bf(v);
        }
      }
    }
  }
}

// ---------------- split-K chain GEMM (latency-optimized) ----------------

template <int KSTEPS>
__global__ __launch_bounds__(256) void gemm_sk(const short* __restrict__ A,
                                               const short* __restrict__ W,
                                               float* __restrict__ part,
                                               int Mrows, long sA) {
  __shared__ __align__(16) short lds[32768];
  const int tid = threadIdx.x;
  const int wave = tid >> 6, lane = tid & 63;
  const int mt = blockIdx.x >> 4, nt = blockIdx.x & 15;
  const int ks = blockIdx.y;
  const int KSPLIT = 32 / KSTEPS;
  const int row0 = mt * 128, col0 = nt * 128;
  const short* Ab = A + (long)blockIdx.z * sA;

  f32x4 acc[4][4];
#pragma unroll
  for (int m = 0; m < 4; ++m)
#pragma unroll
    for (int n = 0; n < 4; ++n) acc[m][n] = (f32x4){0.f, 0.f, 0.f, 0.f};

  const int sr = lane >> 2;
  const int sk = (lane & 3) * 8;
  const int ra0 = wave * 32 + sr;
  const int ra1 = ra0 + 16;
  const int ga0 = (row0 + ra0 < Mrows) ? (row0 + ra0) : (Mrows - 1);
  const int ga1 = (row0 + ra1 < Mrows) ? (row0 + ra1) : (Mrows - 1);
  const long kbase = (long)ks * KSTEPS * 32;
  const short* aP0 = Ab + ((long)ga0 << 10) + kbase + sk;
  const short* aP1 = Ab + ((long)ga1 << 10) + kbase + sk;
  const short* wP0 = W + ((long)(col0 + ra0) << 10) + kbase + sk;
  const short* wP1 = W + ((long)(col0 + ra1) << 10) + kbase + sk;
  const int dA0 = (wave * 2 + 0) * 512, dA1 = (wave * 2 + 1) * 512;
  const int dB0 = 4096 + dA0, dB1 = 4096 + dA1;

  const int fr = lane & 15, fq = lane >> 4;
  const int wr = (wave >> 1) * 64, wc = (wave & 1) * 64;

  auto stage = [&](int kt) {
    short* sb = lds + (kt & 3) * 8192;
    const long ko = (long)kt * 32;
    gl_lds16(aP0 + ko, sb + dA0);
    gl_lds16(aP1 + ko, sb + dA1);
    gl_lds16(wP0 + ko, sb + dB0);
    gl_lds16(wP1 + ko, sb + dB1);
  };
  auto compute = [&](int s) {
    const short* bA = lds + s * 8192;
    const short* bB = bA + 4096;
    bf16x8 af[4], bw[4];
#pragma unroll
    for (int m = 0; m < 4; ++m)
      af[m] = *(const bf16x8*)&bA[(wr + m * 16 + fr) * 32 + fq * 8];
#pragma unroll
    for (int n = 0; n < 4; ++n)
      bw[n] = *(const bf16x8*)&bB[(wc + n * 16 + fr) * 32 + fq * 8];
#pragma unroll
    for (int m = 0; m < 4; ++m)
#pragma unroll
      for (int n = 0; n < 4; ++n)
        acc[m][n] = __builtin_amdgcn_mfma_f32_16x16x32_bf16(af[m], bw[n],
                                                            acc[m][n], 0, 0, 0);
  };

  stage(0); stage(1); stage(2);
#pragma unroll 1
  for (int j = 0; j + 4 <= KSTEPS; ++j) {
    asm volatile("s_waitcnt vmcnt(8)" ::: "memory");
    __builtin_amdgcn_s_barrier();
    compute(j & 3);
    stage(j + 3);
  }
  asm volatile("s_waitcnt vmcnt(8)" ::: "memory");
  __builtin_amdgcn_s_barrier();
  compute((KSTEPS - 3) & 3);
  asm volatile("s_waitcnt vmcnt(4)" ::: "memory");
  __builtin_amdgcn_s_barrier();
  compute((KSTEPS - 2) & 3);
  asm volatile("s_waitcnt vmcnt(0)" ::: "memory");
  __builtin_amdgcn_s_barrier();
  compute((KSTEPS - 1) & 3);

  float* pb = part + ((long)(blockIdx.z * KSPLIT + ks) * Mrows) * 2048;
#pragma unroll
  for (int n = 0; n < 4; ++n) {
    int col = col0 + wc + n * 16 + fr;
#pragma unroll
    for (int m = 0; m < 4; ++m) {
#pragma unroll
      for (int q = 0; q < 4; ++q) {
        int row = row0 + wr + m * 16 + fq * 4 + q;
        if (row < Mrows) pb[(long)row * 2048 + col] = acc[m][n][q];
      }
    }
  }
}

// ---------------- per-level 3-key attention (bf16 children) -------------

__global__ __launch_bounds__(256) void attn_level(
    const short* __restrict__ QKVp, const short* __restrict__ childK, int cs,
    short* __restrict__ ao, int pc, int off, int lgpc) {
  int wid = (blockIdx.x << 2) + (threadIdx.x >> 6);
  if (wid >= B_ * pc) return;
  int lane = threadIdx.x & 63;
  int b = wid >> lgpc;
  int p = wid & (pc - 1);
  int c = lane * 8;
  const short* prow = QKVp + (long)(b * NY + off + p) * 3072 + c;
  const short* c0r = childK + (long)((b * pc + p) * 2) * cs + c;
  const short* c1r = c0r + cs;
  bf16x8 q0 = *(const bf16x8*)(prow);
  bf16x8 q1 = *(const bf16x8*)(prow + 512);
  bf16x8 kp0 = *(const bf16x8*)(prow + 1024);
  bf16x8 kp1 = *(const bf16x8*)(prow + 1536);
  bf16x8 ka0 = *(const bf16x8*)(c0r);
  bf16x8 ka1 = *(const bf16x8*)(c0r + 512);
  bf16x8 kb0 = *(const bf16x8*)(c1r);
  bf16x8 kb1 = *(const bf16x8*)(c1r + 512);
  float d0 = dot8(q0, kp0), d1 = dot8(q1, kp1);
  float d2 = dot8(q0, ka0), d3 = dot8(q1, ka1);
  float d4 = dot8(q0, kb0), d5 = dot8(q1, kb1);
#pragma unroll
  for (int s = 1; s <= 4; s <<= 1) {
    d0 += __shfl_xor(d0, s); d1 += __shfl_xor(d1, s);
    d2 += __shfl_xor(d2, s); d3 += __shfl_xor(d3, s);
    d4 += __shfl_xor(d4, s); d5 += __shfl_xor(d5, s);
  }
  d0 *= 0.125f; d1 *= 0.125f; d2 *= 0.125f;
  d3 *= 0.125f; d4 *= 0.125f; d5 *= 0.125f;
  float mA = fmaxf(d0, fmaxf(d2, d4));
  float e0 = __expf(d0 - mA), e2 = __expf(d2 - mA), e4 = __expf(d4 - mA);
  float iA = 1.f / (e0 + e2 + e4);
  e0 *= iA; e2 *= iA; e4 *= iA;
  float mB = fmaxf(d1, fmaxf(d3, d5));
  float e1 = __expf(d1 - mB), e3 = __expf(d3 - mB), e5 = __expf(d5 - mB);
  float iB = 1.f / (e1 + e3 + e5);
  e1 *= iB; e3 *= iB; e5 *= iB;
  bf16x8 vp0 = *(const bf16x8*)(prow + 2048);
  bf16x8 vp1 = *(const bf16x8*)(prow + 2560);
  bf16x8 va0 = *(const bf16x8*)(c0r + 1024);
  bf16x8 va1 = *(const bf16x8*)(c0r + 1536);
  bf16x8 vb0 = *(const bf16x8*)(c1r + 1024);
  bf16x8 vb1 = *(const bf16x8*)(c1r + 1536);
  bf16x8 s0, s1;
#pragma unroll
  for (int j = 0; j < 8; ++j) {
    s0[j] = f2bf(e0 * b2f(vp0[j]) + e2 * b2f(va0[j]) + e4 * b2f(vb0[j]));
    s1[j] = f2bf(e1 * b2f(vp1[j]) + e3 * b2f(va1[j]) + e5 * b2f(vb1[j]));
  }
  short* orow = ao + (long)(b * NY + off + p) * 1024 + c;
  *(bf16x8*)orow = s0;
  *(bf16x8*)(orow + 512) = s1;
}

// ---------------- per-level 3-key attention (f32 split-K partials) -------

template <int KS>
__device__ __forceinline__ void load8sum(const float* p, long kstride,
                                         float* o) {
  float4 a = *(const float4*)p, b = *(const float4*)(p + 4);
  o[0] = a.x; o[1] = a.y; o[2] = a.z; o[3] = a.w;
  o[4] = b.x; o[5] = b.y; o[6] = b.z; o[7] = b.w;
#pragma unroll
  for (int ks = 1; ks < KS; ++ks) {
    const float* q = p + ks * kstride;
    float4 c = *(const float4*)q, d = *(const float4*)(q + 4);
    o[0] += c.x; o[1] += c.y; o[2] += c.z; o[3] += c.w;
    o[4] += d.x; o[5] += d.y; o[6] += d.z; o[7] += d.w;
  }
}
__device__ __forceinline__ float dot8f(bf16x8 a, const float* b) {
  float s = 0.f;
#pragma unroll
  for (int j = 0; j < 8; ++j) s += b2f(a[j]) * b[j];
  return s;
}

template <int KS>
__global__ __launch_bounds__(256) void attn_level_sk(
    const short* __restrict__ QKVp, const float* __restrict__ part,
    short* __restrict__ ao, int pc, int off, int lgpc) {
  int wid = (blockIdx.x << 2) + (threadIdx.x >> 6);
  if (wid >= B_ * pc) return;
  int lane = threadIdx.x & 63;
  int b = wid >> lgpc;
  int p = wid & (pc - 1);
  int c = lane * 8;
  const int cc = pc * 2;
  const long kstride = (long)cc * 2048;
  const short* prow = QKVp + (long)(b * NY + off + p) * 3072 + c;
  const float* c0r = part + (long)(b * KS) * kstride + (long)(p * 2) * 2048 + c;
  const float* c1r = c0r + 2048;
  bf16x8 q0 = *(const bf16x8*)(prow);
  bf16x8 q1 = *(const bf16x8*)(prow + 512);
  bf16x8 kp0 = *(const bf16x8*)(prow + 1024);
  bf16x8 kp1 = *(const bf16x8*)(prow + 1536);
  float ka0[8], ka1[8], kb0[8], kb1[8];
  load8sum<KS>(c0r, kstride, ka0);
  load8sum<KS>(c0r + 512, kstride, ka1);
  load8sum<KS>(c1r, kstride, kb0);
  load8sum<KS>(c1r + 512, kstride, kb1);
  float d0 = dot8(q0, kp0), d1 = dot8(q1, kp1);
  float d2 = dot8f(q0, ka0), d3 = dot8f(q1, ka1);
  float d4 = dot8f(q0, kb0), d5 = dot8f(q1, kb1);
#pragma unroll
  for (int s = 1; s <= 4; s <<= 1) {
    d0 += __shfl_xor(d0, s); d1 += __shfl_xor(d1, s);
    d2 += __shfl_xor(d2, s); d3 += __shfl_xor(d3, s);
    d4 += __shfl_xor(d4, s); d5 += __shfl_xor(d5, s);
  }
  d0 *= 0.125f; d1 *= 0.125f; d2 *= 0.125f;
  d3 *= 0.125f; d4 *= 0.125f; d5 *= 0.125f;
  float mA = fmaxf(d0, fmaxf(d2, d4));
  float e0 = __expf(d0 - mA), e2 = __expf(d2 - mA), e4 = __expf(d4 - mA);
  float iA = 1.f / (e0 + e2 + e4);
  e0 *= iA; e2 *= iA; e4 *= iA;
  float mB = fmaxf(d1, fmaxf(d3, d5));
  float e1 = __expf(d1 - mB), e3 = __expf(d3 - mB), e5 = __expf(d5 - mB);
  float iB = 1.f / (e1 + e3 + e5);
  e1 *= iB; e3 *= iB; e5 *= iB;
  bf16x8 vp0 = *(const bf16x8*)(prow + 2048);
  bf16x8 vp1 = *(const bf16x8*)(prow + 2560);
  float va0[8], va1[8], vb0[8], vb1[8];
  load8sum<KS>(c0r + 1024, kstride, va0);
  load8sum<KS>(c0r + 1536, kstride, va1);
  load8sum<KS>(c1r + 1024, kstride, vb0);
  load8sum<KS>(c1r + 1536, kstride, vb1);
  bf16x8 s0, s1;
#pragma unroll
  for (int j = 0; j < 8; ++j) {
    s0[j] = f2bf(e0 * b2f(vp0[j]) + e2 * va0[j] + e4 * vb0[j]);
    s1[j] = f2bf(e1 * b2f(vp1[j]) + e3 * va1[j] + e5 * vb1[j]);
  }
  short* orow = ao + (long)(b * NY + off + p) * 1024 + c;
  *(bf16x8*)orow = s0;
  *(bf16x8*)(orow + 512) = s1;
}

// ---------------- final 13-key sparse attention ----------------

__global__ __launch_bounds__(256) void attn_final(const short* __restrict__ QKVx,
                                                  short* __restrict__ out) {
  const long XLEN = (long)B_ * N_ * 3072;
  int wid = (blockIdx.x << 2) + (threadIdx.x >> 6);
  int lane = threadIdx.x & 63;
  int b = wid >> 12;
  int i = wid & (N_ - 1);
  int c = lane * 8;
  const short* qrow = QKVx + (long)(b * N_ + i) * 3072;
  bf16x8 q0 = *(const bf16x8*)(qrow + c);
  bf16x8 q1 = *(const bf16x8*)(qrow + 512 + c);

  long offs[13];
  unsigned mbits = 0;
  offs[0] = (long)(b * N_ + i) * 3072 + 1024;
  int ncur = i;
#pragma unroll
  for (int lvl = 0; lvl < 12; ++lvl) {
    int pair, nx;
    if (lvl == 0) { pair = ncur; nx = ncur ^ 1; }
    else { pair = (ncur >> 1) + N_; nx = pair ^ 1; }
    bool valid = nx <= 2 * N_ - 3;
    int r = valid ? nx : (2 * N_ - 2);
    if (valid && pair < nx) mbits |= 1u << (lvl + 1);
    offs[lvl + 1] = (r < N_) ? ((long)(b * N_ + r) * 3072 + 1024)
                             : (XLEN + (long)(b * NY + (r - N_)) * 2048);
    ncur = nx;
  }
  float dA[13], dB[13];
#pragma unroll
  for (int k = 0; k < 13; ++k) {
    const short* kb = QKVx + offs[k];
    dA[k] = dot8(q0, *(const bf16x8*)(kb + c));
    dB[k] = dot8(q1, *(const bf16x8*)(kb + 512 + c));
  }
#pragma unroll
  for (int s = 1; s <= 4; s <<= 1) {
#pragma unroll
    for (int k = 0; k < 13; ++k) {
      dA[k] += __shfl_xor(dA[k], s);
      dB[k] += __shfl_xor(dB[k], s);
    }
  }
  float mA = -1e30f, mB = -1e30f;
#pragma unroll
  for (int k = 0; k < 13; ++k) {
    bool msk = (mbits >> k) & 1;
    dA[k] = msk ? -1e30f : dA[k] * 0.125f;
    dB[k] = msk ? -1e30f : dB[k] * 0.125f;
    mA = fmaxf(mA, dA[k]);
    mB = fmaxf(mB, dB[k]);
  }
  float sA = 0.f, sB = 0.f;
#pragma unroll
  for (int k = 0; k < 13; ++k) {
    dA[k] = __expf(dA[k] - mA); sA += dA[k];
    dB[k] = __expf(dB[k] - mB); sB += dB[k];
  }
  float iA = 1.f / sA, iB = 1.f / sB;
  float o0[8] = {0, 0, 0, 0, 0, 0, 0, 0};
  float o1[8] = {0, 0, 0, 0, 0, 0, 0, 0};
#pragma unroll
  for (int k = 0; k < 13; ++k) {
    const short* vb = QKVx + offs[k] + 1024;
    bf16x8 v0 = *(const bf16x8*)(vb + c);
    bf16x8 v1 = *(const bf16x8*)(vb + 512 + c);
    float wA = dA[k] * iA, wB = dB[k] * iB;
#pragma unroll
    for (int j = 0; j < 8; ++j) {
      o0[j] += wA * b2f(v0[j]);
      o1[j] += wB * b2f(v1[j]);
    }
  }
  bf16x8 s0, s1;
#pragma unroll
  for (int j = 0; j < 8; ++j) { s0[j] = f2bf(o0[j]); s1[j] = f2bf(o1[j]); }
  short* orow = out + (long)(b * N_ + i) * 1024 + c;
  *(bf16x8*)orow = s0;
  *(bf16x8*)(orow + 512) = s1;
}

// ---------------- host orchestration ----------------

extern "C" void kernel_launch(void* const* d_in, const int* in_sizes, int n_in,
                              void* d_out, int out_size, void* d_ws,
                              size_t ws_size, hipStream_t stream) {
  const float* x = (const float*)d_in[0];
  const float* boy = (const float*)d_in[5];
  const float* box = (const float*)d_in[10];

  char* pw = (char*)d_ws;
  auto alloc = [&](size_t n) {
    char* r = pw;
    pw += (n + 255) & ~(size_t)255;
    return r;
  };
  short* xbf   = (short*)alloc((size_t)B_ * N_ * 1024 * 2);
  // QKVx slot doubles as XQKVy until level-0 attn done; KVy contiguous after.
  short* QKVx  = (short*)alloc((size_t)B_ * N_ * 3072 * 2);
  short* KVy   = (short*)alloc((size_t)B_ * NY * 2048 * 2);
  short* QKVp  = (short*)alloc((size_t)B_ * NY * 3072 * 2);
  short* KVc   = (short*)alloc((size_t)B_ * 4096 * 2048 * 2);
  short* ao    = (short*)alloc((size_t)B_ * NY * 1024 * 2);
  short* aout  = (short*)alloc((size_t)B_ * N_ * 1024 * 2);
  short* wts   = (short*)alloc((size_t)8 * 1048576 * 2);
  short* woyT  = (short*)alloc((size_t)1048576 * 2);
  short* mkmv  = (short*)alloc((size_t)2 * 1048576 * 2);
  float* cbias = (float*)alloc((size_t)2048 * 4);
  float* part  = (float*)KVc;   // alias: time-disjoint with bf16 KVc use
  short* XQ    = QKVx;          // alias: XQKVy lives in the QKVx slot early

  CvtArgs ca;
  ca.x = x;
  ca.w[0] = (const float*)d_in[1];  // Wq_y
  ca.w[1] = (const float*)d_in[2];  // Wk_y
  ca.w[2] = (const float*)d_in[3];  // Wv_y
  ca.w[3] = (const float*)d_in[6];  // Wq_x
  ca.w[4] = (const float*)d_in[7];  // Wk_x
  ca.w[5] = (const float*)d_in[8];  // Wv_x
  ca.w[6] = (const float*)d_in[4];  // Wo_y
  ca.w[7] = (const float*)d_in[9];  // Wo_x
  ca.woy = (const float*)d_in[4];
  ca.wkx = (const float*)d_in[7];
  ca.wvx = (const float*)d_in[8];
  ca.boy = boy;
  ca.xbf = xbf;
  ca.wts = wts;
  ca.woyT = woyT;
  ca.cbias = cbias;
  cvt_all<<<17152, 256, 0, stream>>>(ca);

  const long SX = (long)N_ * 1024, SY = (long)NY * 1024;
  short* wy  = wts;                          // [Wqy|Wky|Wvy]
  short* wkv = wts + (size_t)4 * 1048576;    // [Wkx|Wvx]
  short* wx  = wts + (size_t)3 * 1048576;    // [Wqx|Wkx|Wvx]
  short* wox = wts + (size_t)7 * 1048576;

  auto gemm = [&](const short* A, const short* W, void* C, const float* bias,
                  int Mb, int Nc, long sA, long sC, int f32o, int nb) {
    dim3 g((Mb + 127) / 128, Nc / 128, nb);
    if (f32o)
      gemm_bt<1, 1><<<g, 256, 0, stream>>>(A, W, C, bias, Mb, Nc, sA, sC);
    else if (bias)
      gemm_bt<0, 1><<<g, 256, 0, stream>>>(A, W, C, bias, Mb, Nc, sA, sC);
    else
      gemm_bt<0, 0><<<g, 256, 0, stream>>>(A, W, C, nullptr, Mb, Nc, sA, sC);
  };

  // weight fold: [Mk;Mv] = [Wkx;Wvx] @ WoyT
  gemm(wkv, woyT, mkmv, nullptr, 2048, 1024, 0, 0, 0, 1);

  // XQKVy = x @ [Wqy|Wky|Wvy]^T ; pooled tree = cascade-pooled XQKVy
  gemm(xbf, wy, XQ, nullptr, 4096, 3072, SX, (long)N_ * 3072, 0, B_);
  pool_cascade<<<B_ * 256 * 3, 256, 0, stream>>>(XQ, QKVp);
  pool_qkv_b<<<dim3(128, 3), 256, 0, stream>>>(QKVp);

  // level 0: children K/V are XQKVy x-rows (stride 3072, K at +1024)
  attn_level<<<(B_ * 2048) / 4, 256, 0, stream>>>(QKVp, XQ + 1024, 3072, ao,
                                                  2048, 0, 11);

  int offl = 0, pcl = 2048;
  for (int l = 1; l < 12; ++l) {
    int offprev = offl;
    offl += pcl;
    pcl >>= 1;
    int cc = pcl * 2;
    const short* prev = ao + (long)offprev * 1024;
    int blocks = (B_ * pcl + 3) / 4;
    if (cc == 1024) {        // level 2: split-K=2
      dim3 g((cc / 128) * 16, 2, B_);
      gemm_sk<16><<<g, 256, 0, stream>>>(prev, wy + 1048576, part, cc, SY);
      attn_level_sk<2><<<blocks, 256, 0, stream>>>(QKVp, part, ao, pcl, offl,
                                                   11 - l);
    } else if (cc <= 512) {  // levels 3..11: split-K=4
      dim3 g(((cc + 127) / 128) * 16, 4, B_);
      gemm_sk<8><<<g, 256, 0, stream>>>(prev, wy + 1048576, part, cc, SY);
      attn_level_sk<4><<<blocks, 256, 0, stream>>>(QKVp, part, ao, pcl, offl,
                                                   11 - l);
    } else {                 // level 1: full-K
      gemm(prev, wy + 1048576, KVc, nullptr, cc, 2048, SY, (long)cc * 2048, 0,
           B_);
      attn_level<<<blocks, 256, 0, stream>>>(QKVp, KVc, 2048, ao, pcl, offl,
                                             11 - l);
    }
  }

  // KVy = ao @ [Mk;Mv]^T + cbias ; QKVx = x @ [Wqx|Wkx|Wvx]^T
  gemm(ao, mkmv, KVy, cbias, NY, 2048, SY, (long)NY * 2048, 0, B_);
  gemm(xbf, wx, QKVx, nullptr, 4096, 3072, SX, (long)N_ * 3072, 0, B_);

  attn_final<<<(B_ * N_) / 4, 256, 0, stream>>>(QKVx, aout);

  gemm(aout, wox, d_out, box, 4096, 1024, SX, SX, 1, B_);
}